// Round 5
// baseline (509.815 us; speedup 1.0000x reference)
//
#include <hip/hip_runtime.h>

// ---- workspace layout (bytes) ----
#define IDENTP_OFF 0u            // identp: 8*3*98*100*2 = 470400
#define HMP_OFF    470400u       // hmp: 256*98*100*2 = 5017600
#define ACT1P_OFF  5488000u      // act1p: 256*64*50*52*2 = 85196800 (ends 90684800)
#define ACT3P_OFF  470400u       // act3p: 256*50*50*64*2 = 81920000 — ALIASES hmp+act1p (dead after conv2)
#define ACT2P_OFF  90684800u     // act2p: 256*26*26*128*2 = 44302336
#define W2A_OFF    134987136u    // w2a: 128*1024*2 = 262144
#define W3A_OFF    135249280u    // w3a: 4*64*512*2 = 262144
#define W1B_OFF    135511424u    // w1b: 64*64*2 = 8192
#define W4C_OFF    135519616u    // w4c: 16*576*2 = 18432  (end 135538048)

using short8  = __attribute__((ext_vector_type(8))) short;
using floatx4 = __attribute__((ext_vector_type(4))) float;
union UV { uint4 u; short8 s; };

static __device__ __forceinline__ float bf2f(unsigned short u) {
  union { unsigned int i; float f; } v; v.i = ((unsigned int)u) << 16; return v.f;
}
static __device__ __forceinline__ unsigned short f2bf(float f) {
  union { float f; unsigned int i; } v; v.f = f;
  unsigned int x = v.i;
  return (unsigned short)((x + 0x7FFFu + ((x >> 16) & 1u)) >> 16);  // RNE
}
static __device__ __forceinline__ uint4 pack8(const unsigned short* v) {
  uint4 p;
  p.x = (unsigned)v[0] | ((unsigned)v[1] << 16);
  p.y = (unsigned)v[2] | ((unsigned)v[3] << 16);
  p.z = (unsigned)v[4] | ((unsigned)v[5] << 16);
  p.w = (unsigned)v[6] | ((unsigned)v[7] << 16);
  return p;
}
static __device__ __forceinline__ float ftanh(float x) {
  x = fminf(fmaxf(x, -10.f), 10.f);
  float e = __expf(2.f * x);
  return (e - 1.f) * __builtin_amdgcn_rcpf(e + 1.f);
}

// ============ prep: heatmap(padded), identp, weight casts, pad zeroing ============
__global__ __launch_bounds__(256) void prep_kernel(
    const float* __restrict__ lm, const float* __restrict__ ident,
    const float* __restrict__ w1, const float* __restrict__ w2,
    const float* __restrict__ w3, const float* __restrict__ w4,
    unsigned short* __restrict__ identp, unsigned short* __restrict__ hmp,
    unsigned short* __restrict__ w1b, unsigned short* __restrict__ w2a,
    unsigned short* __restrict__ w3a, unsigned short* __restrict__ w4c,
    unsigned short* __restrict__ act1p, unsigned short* __restrict__ act2p) {
  int bid = blockIdx.x, tid = threadIdx.x;
  if (bid < 256) {
    // hmp [bt][98][100]: zero then scatter landmarks at (+1,+1)
    unsigned int* h32 = (unsigned int*)(hmp + bid * 9800);
    for (int i = tid; i < 4900; i += 256) h32[i] = 0u;
    __syncthreads();
    if (tid < 68) {
      float x = lm[bid * 136 + tid * 2 + 0] * 95.0f;
      float y = lm[bid * 136 + tid * 2 + 1] * 95.0f;
      int ix = (int)x, iy = (int)y;
      if (ix >= 0 && ix < 96 && iy >= 0 && iy < 96)
        hmp[bid * 9800 + (iy + 1) * 100 + (ix + 1)] = 0x3F80;  // bf16 1.0
    }
  } else if (bid < 320) {
    int e = (bid - 256) * 2048 + tid * 8;  // w2 flat [128][1024], k=ic*16+kh*4+kw
    float4 f0 = *(const float4*)(w2 + e);
    float4 f1 = *(const float4*)(w2 + e + 4);
    unsigned short v[8] = { f2bf(f0.x), f2bf(f0.y), f2bf(f0.z), f2bf(f0.w),
                            f2bf(f1.x), f2bf(f1.y), f2bf(f1.z), f2bf(f1.w) };
    *(uint4*)(w2a + e) = pack8(v);
  } else if (bid < 384) {
    int e = (bid - 320) * 2048 + tid * 8;  // w3a [cls][oc64][k512], k=(a*2+b)*128+ic
    unsigned short v[8];
#pragma unroll
    for (int j = 0; j < 8; j++) {
      int k = e + j;
      int cls = k >> 15, rem = k & 32767;
      int oc = rem >> 9, kidx = rem & 511;
      int ab = kidx >> 7, ic = kidx & 127;
      int a = ab >> 1, b = ab & 1;
      int r = cls >> 1, s = cls & 1;
      int kh = 2 * a + 1 - r, kw = 2 * b + 1 - s;
      v[j] = f2bf(w3[((ic * 64 + oc) * 4 + kh) * 4 + kw]);
    }
    *(uint4*)(w3a + e) = pack8(v);
  } else if (bid < 408) {
    // identp [b*3+ic][98][100] bf16, interior rows/cols 1..96
    int bci = bid - 384;
    const float* src = ident + bci * 9216;
    unsigned short* dst = identp + bci * 9800;
    for (int i = tid; i < 9800; i += 256) {
      int row = i / 100, col = i - row * 100;
      bool in = (row >= 1) && (row <= 96) && (col >= 1) && (col <= 96);
      dst[i] = in ? f2bf(src[(row - 1) * 96 + (col - 1)]) : (unsigned short)0;
    }
  } else if (bid < 664) {
    // act1p halo zero, one block per frame: [ic][50][52], data rows1..48 cols1..48
    unsigned short* base = act1p + (size_t)(bid - 408) * 166400u;
    for (int idx = tid; idx < 18944; idx += 256) {
      int ic = idx / 296;
      int e = idx - ic * 296;
      int o;
      if (e < 53) o = e;
      else if (e < 241) { int q = (e - 53) >> 2; int m = (e - 53) & 3;
                          o = (q + 1) * 52 + 49 + m; }
      else o = 2545 + (e - 241);
      base[ic * 2600 + o] = 0;
    }
  } else if (bid < 920) {
    // act2p halo zero, one block per frame: [26][26][128] channel-last
    uint4* b4p = (uint4*)(act2p + (size_t)(bid - 664) * 86528u);
    uint4 z = {0, 0, 0, 0};
    for (int c = tid; c < 1600; c += 256) {
      int cell = c >> 4, v = c & 15;
      int row, col;
      if (cell < 26) { row = 0; col = cell; }
      else if (cell < 52) { row = 25; col = cell - 26; }
      else if (cell < 76) { row = cell - 51; col = 0; }
      else { row = cell - 75; col = 25; }
      b4p[(row * 26 + col) * 16 + v] = z;
    }
  } else if (bid == 920) {
    // w1b [64][64] bf16 (w1 flat is already [oc][ic*16+kh*4+kw])
    int e = tid * 16;
    unsigned short v[16];
#pragma unroll
    for (int q = 0; q < 4; q++) {
      float4 f = *(const float4*)(w1 + e + q * 4);
      v[q * 4 + 0] = f2bf(f.x); v[q * 4 + 1] = f2bf(f.y);
      v[q * 4 + 2] = f2bf(f.z); v[q * 4 + 3] = f2bf(f.w);
    }
    *(uint4*)(w1b + e) = pack8(v);
    *(uint4*)(w1b + e + 8) = pack8(v + 8);
  } else {
    // w4c [n16][k576]: k = (dh*3+dw)*64 + ic; n = cls*3+oc (n>=12 -> 0)
    for (int idx = tid; idx < 9216; idx += 256) {
      int n = idx / 576, k = idx - n * 576;
      int t = k >> 6, ic = k & 63;
      int dh = t / 3, dw = t - dh * 3;
      unsigned short val = 0;
      if (n < 12) {
        int cls = n / 3, oc = n - cls * 3;
        int r = cls >> 1, s = cls & 1;
        int a = r - dh + 1, b = s - dw + 1;
        if (a >= 0 && a < 2 && b >= 0 && b < 2) {
          int kh = 2 * a + 1 - r, kw = 2 * b + 1 - s;
          val = f2bf(w4[ic * 48 + oc * 16 + kh * 4 + kw]);
        }
      }
      w4c[idx] = val;
    }
  }
}

// ============ conv1 (MFMA): identp+hmp -> relu -> act1p [BT][64][50][52] ============
__global__ __launch_bounds__(256) void conv1_kernel(
    const unsigned short* __restrict__ identp, const unsigned short* __restrict__ hmp,
    const unsigned short* __restrict__ w1b, const float* __restrict__ b1,
    unsigned short* __restrict__ act1p) {
  __shared__ unsigned short Blds[64 * 72];  // [n][k64 + pad8]
  int tid = threadIdx.x;
  int nb = blockIdx.x, bt = blockIdx.y;
  int b = bt >> 5;
  int wave = tid >> 6, lane = tid & 63, quad = lane >> 4, l16 = lane & 15;
  int nB = tid & 63, g = tid >> 6;
  int pB = nb * 64 + nB;
  int ohB = pB / 48, owB = pB % 48;

#pragma unroll
  for (int ks = 0; ks < 2; ks++) {
    int k0 = ks * 32 + g * 8;
    int ic = k0 >> 4, khp = (k0 >> 3) & 1;
    const unsigned short* src = (ic < 3) ? identp + (b * 3 + ic) * 9800
                                         : hmp + bt * 9800;
    const unsigned short* p = src + (2 * ohB + khp * 2) * 100 + 2 * owB;
    uint4 bv;
    bv.x = *(const unsigned int*)(p);
    bv.y = *(const unsigned int*)(p + 2);
    bv.z = *(const unsigned int*)(p + 100);
    bv.w = *(const unsigned int*)(p + 102);
    *(uint4*)(&Blds[nB * 72 + k0]) = bv;
  }
  const unsigned short* aptr = w1b + (wave * 16 + l16) * 64 + quad * 8;
  UV a0, a1;
  a0.u = *(const uint4*)(aptr);
  a1.u = *(const uint4*)(aptr + 32);
  __syncthreads();

  floatx4 acc[4];
#pragma unroll
  for (int nf = 0; nf < 4; nf++) acc[nf] = (floatx4){0.f, 0.f, 0.f, 0.f};
#pragma unroll
  for (int nf = 0; nf < 4; nf++) {
    UV b0, b1v;
    b0.u = *(const uint4*)(&Blds[(nf * 16 + l16) * 72 + quad * 8]);
    b1v.u = *(const uint4*)(&Blds[(nf * 16 + l16) * 72 + 32 + quad * 8]);
    acc[nf] = __builtin_amdgcn_mfma_f32_16x16x32_bf16(a0.s, b0.s, acc[nf], 0, 0, 0);
    acc[nf] = __builtin_amdgcn_mfma_f32_16x16x32_bf16(a1.s, b1v.s, acc[nf], 0, 0, 0);
  }

  float4 bb = *(const float4*)(b1 + wave * 16 + quad * 4);
  unsigned short* obase = act1p + (size_t)bt * 166400u;
#pragma unroll
  for (int nf = 0; nf < 4; nf++) {
    int p = nb * 64 + nf * 16 + l16;
    int oh = p / 48, ow = p % 48;
    unsigned short* dst = obase + (oh + 1) * 52 + (ow + 1);
#pragma unroll
    for (int reg = 0; reg < 4; reg++) {
      int oc = wave * 16 + quad * 4 + reg;
      float bias = (reg == 0) ? bb.x : (reg == 1) ? bb.y : (reg == 2) ? bb.z : bb.w;
      dst[oc * 2600] = f2bf(fmaxf(acc[nf][reg] + bias, 0.f));
    }
  }
}

// ============ conv2 (MFMA): act1p -> relu -> act2p [26][26][128] channel-last ============
__global__ __launch_bounds__(256) void conv2_kernel(
    const unsigned short* __restrict__ act1p, const unsigned short* __restrict__ w2a,
    const float* __restrict__ b2, unsigned short* __restrict__ act2p) {
  __shared__ unsigned short Blds[2][64 * 40];
  int tid = threadIdx.x;
  int nb = blockIdx.x, bt = blockIdx.y;
  int wave = tid >> 6, lane = tid & 63, quad = lane >> 4, l16 = lane & 15;
  int nB = tid & 63, g = tid >> 6;
  int icl = g >> 1, khp = g & 1;
  int pB = nb * 64 + nB;
  int ohB = pB / 24, owB = pB % 24;
  const unsigned short* gbase =
      act1p + (size_t)bt * 166400u + icl * 2600 + (2 * ohB + khp * 2) * 52 + 2 * owB;
  const unsigned short* aptr0 = w2a + (wave * 32 + l16) * 1024 + quad * 8;
  const unsigned short* aptr1 = aptr0 + 16 * 1024;

  floatx4 acc[2][4];
#pragma unroll
  for (int i = 0; i < 2; i++)
#pragma unroll
    for (int j = 0; j < 4; j++) acc[i][j] = (floatx4){0.f, 0.f, 0.f, 0.f};

  uint4 bv;
  bv.x = *(const unsigned int*)(gbase);
  bv.y = *(const unsigned int*)(gbase + 2);
  bv.z = *(const unsigned int*)(gbase + 52);
  bv.w = *(const unsigned int*)(gbase + 54);
  *(uint4*)(&Blds[0][nB * 40 + g * 8]) = bv;
  UV a_cur0, a_cur1, a_nxt0, a_nxt1;
  a_cur0.u = *(const uint4*)(aptr0);
  a_cur1.u = *(const uint4*)(aptr1);
  __syncthreads();

  for (int kk = 0; kk < 32; kk++) {
    int cur = kk & 1;
    UV bfrag[4];
#pragma unroll
    for (int nf = 0; nf < 4; nf++)
      bfrag[nf].u = *(const uint4*)(&Blds[cur][(nf * 16 + l16) * 40 + quad * 8]);
    uint4 bnv;
    if (kk < 31) {
      const unsigned short* p = gbase + (kk + 1) * 5200;  // 2 ic per K-step
      bnv.x = *(const unsigned int*)(p);
      bnv.y = *(const unsigned int*)(p + 2);
      bnv.z = *(const unsigned int*)(p + 52);
      bnv.w = *(const unsigned int*)(p + 54);
      a_nxt0.u = *(const uint4*)(aptr0 + (kk + 1) * 32);
      a_nxt1.u = *(const uint4*)(aptr1 + (kk + 1) * 32);
    }
#pragma unroll
    for (int nf = 0; nf < 4; nf++) {
      acc[0][nf] = __builtin_amdgcn_mfma_f32_16x16x32_bf16(a_cur0.s, bfrag[nf].s, acc[0][nf], 0, 0, 0);
      acc[1][nf] = __builtin_amdgcn_mfma_f32_16x16x32_bf16(a_cur1.s, bfrag[nf].s, acc[1][nf], 0, 0, 0);
    }
    if (kk < 31) *(uint4*)(&Blds[1 - cur][nB * 40 + g * 8]) = bnv;
    __syncthreads();
    a_cur0 = a_nxt0; a_cur1 = a_nxt1;
  }

  unsigned short* obase = act2p + (size_t)bt * 86528u;
#pragma unroll
  for (int mf = 0; mf < 2; mf++) {
    int oc0 = wave * 32 + mf * 16 + quad * 4;
    float4 bb = *(const float4*)(b2 + oc0);
#pragma unroll
    for (int nf = 0; nf < 4; nf++) {
      int p = nb * 64 + nf * 16 + l16;
      int oh = p / 24, ow = p % 24;
      float v0 = fmaxf(acc[mf][nf][0] + bb.x, 0.f);
      float v1 = fmaxf(acc[mf][nf][1] + bb.y, 0.f);
      float v2 = fmaxf(acc[mf][nf][2] + bb.z, 0.f);
      float v3 = fmaxf(acc[mf][nf][3] + bb.w, 0.f);
      uint2 o;
      o.x = (unsigned)f2bf(v0) | ((unsigned)f2bf(v1) << 16);
      o.y = (unsigned)f2bf(v2) | ((unsigned)f2bf(v3) << 16);
      *(uint2*)(obase + ((oh + 1) * 26 + (ow + 1)) * 128 + oc0) = o;
    }
  }
}

// ============ deconv3 (MFMA): act2p -> relu -> act3p [BT][50][50][64] ch-last padded ============
__global__ __launch_bounds__(256) void deconv3_kernel(
    const unsigned short* __restrict__ act2p, const unsigned short* __restrict__ w3a,
    const float* __restrict__ b3, unsigned short* __restrict__ act3p) {
  __shared__ unsigned short Blds[2][2][64 * 40];
  int tid = threadIdx.x;
  int nb = blockIdx.x, r = blockIdx.y, bt = blockIdx.z;
  int wave = tid >> 6, lane = tid & 63, quad = lane >> 4, l16 = lane & 15;
  int nB = tid & 63, g = tid >> 6;
  int pB = nb * 64 + nB;
  int iB = pB / 24, jB = pB % 24;
  const unsigned short* a2 = act2p + (size_t)bt * 86528u;
  const unsigned short* A0 = w3a + (r * 2) * 32768 + (wave * 16 + l16) * 512 + quad * 8;
  const unsigned short* A1 = A0 + 32768;
  unsigned short* a3 = act3p + (size_t)bt * 160000u;

  // halo zero for this frame's act3p (one block per frame does it)
  if (nb == 0 && r == 0) {
    uint4* hz = (uint4*)a3;
    uint4 z = {0, 0, 0, 0};
    for (int c = tid; c < 1568; c += 256) {
      int cell = c >> 3, v = c & 7;
      int row, col;
      if (cell < 50) { row = 0; col = cell; }
      else if (cell < 100) { row = 49; col = cell - 50; }
      else if (cell < 148) { row = cell - 99; col = 0; }
      else { row = cell - 147; col = 49; }
      hz[(row * 50 + col) * 8 + v] = z;
    }
  }

  floatx4 acc[2][4];
#pragma unroll
  for (int i = 0; i < 2; i++)
#pragma unroll
    for (int j = 0; j < 4; j++) acc[i][j] = (floatx4){0.f, 0.f, 0.f, 0.f};

  {
    int row = iB + r + 1;
    const unsigned short* p = a2 + (row * 26 + jB + 1) * 128 + g * 8;
    uint4 b0 = *(const uint4*)(p);
    uint4 b1 = *(const uint4*)(p + 128);
    *(uint4*)(&Blds[0][0][nB * 40 + g * 8]) = b0;
    *(uint4*)(&Blds[0][1][nB * 40 + g * 8]) = b1;
  }
  UV a_cur0, a_cur1, a_nxt0, a_nxt1;
  a_cur0.u = *(const uint4*)(A0);
  a_cur1.u = *(const uint4*)(A1);
  __syncthreads();

  for (int kk = 0; kk < 16; kk++) {
    int cur = kk & 1;
    UV bfrag[2][4];
#pragma unroll
    for (int s = 0; s < 2; s++)
#pragma unroll
      for (int nf = 0; nf < 4; nf++)
        bfrag[s][nf].u = *(const uint4*)(&Blds[cur][s][(nf * 16 + l16) * 40 + quad * 8]);
    uint4 bn0, bn1;
    if (kk < 15) {
      int kn = kk + 1;
      int ab = kn >> 2, ic0 = (kn & 3) * 32;
      int a = ab >> 1, b = ab & 1;
      int row = iB + r - a + 1;
      const unsigned short* p = a2 + (row * 26 + jB + 1 - b) * 128 + ic0 + g * 8;
      bn0 = *(const uint4*)(p);
      bn1 = *(const uint4*)(p + 128);
      a_nxt0.u = *(const uint4*)(A0 + kn * 32);
      a_nxt1.u = *(const uint4*)(A1 + kn * 32);
    }
#pragma unroll
    for (int nf = 0; nf < 4; nf++) {
      acc[0][nf] = __builtin_amdgcn_mfma_f32_16x16x32_bf16(a_cur0.s, bfrag[0][nf].s, acc[0][nf], 0, 0, 0);
      acc[1][nf] = __builtin_amdgcn_mfma_f32_16x16x32_bf16(a_cur1.s, bfrag[1][nf].s, acc[1][nf], 0, 0, 0);
    }
    if (kk < 15) {
      *(uint4*)(&Blds[1 - cur][0][nB * 40 + g * 8]) = bn0;
      *(uint4*)(&Blds[1 - cur][1][nB * 40 + g * 8]) = bn1;
    }
    __syncthreads();
    a_cur0 = a_nxt0; a_cur1 = a_nxt1;
  }

  // epilogue: channel-last padded; pack 4 consecutive oc -> uint2 per (pixel)
  float4 bb = *(const float4*)(b3 + wave * 16 + quad * 4);
  int oc0 = wave * 16 + quad * 4;
#pragma unroll
  for (int nf = 0; nf < 4; nf++) {
    int n = nb * 64 + nf * 16 + l16;
    int i = n / 24, j = n % 24;
    int oh = 2 * i + r;
    float v00 = fmaxf(acc[0][nf][0] + bb.x, 0.f);
    float v01 = fmaxf(acc[0][nf][1] + bb.y, 0.f);
    float v02 = fmaxf(acc[0][nf][2] + bb.z, 0.f);
    float v03 = fmaxf(acc[0][nf][3] + bb.w, 0.f);
    float v10 = fmaxf(acc[1][nf][0] + bb.x, 0.f);
    float v11 = fmaxf(acc[1][nf][1] + bb.y, 0.f);
    float v12 = fmaxf(acc[1][nf][2] + bb.z, 0.f);
    float v13 = fmaxf(acc[1][nf][3] + bb.w, 0.f);
    uint2 q0, q1;
    q0.x = (unsigned)f2bf(v00) | ((unsigned)f2bf(v01) << 16);
    q0.y = (unsigned)f2bf(v02) | ((unsigned)f2bf(v03) << 16);
    q1.x = (unsigned)f2bf(v10) | ((unsigned)f2bf(v11) << 16);
    q1.y = (unsigned)f2bf(v12) | ((unsigned)f2bf(v13) << 16);
    *(uint2*)(a3 + ((oh + 1) * 50 + (2 * j + 1)) * 64 + oc0) = q0;  // s=0 (ow=2j)
    *(uint2*)(a3 + ((oh + 1) * 50 + (2 * j + 2)) * 64 + oc0) = q1;  // s=1 (ow=2j+1)
  }
}

// ============ deconv4 (MFMA, LDS-free) + tanh: act3p -> out fp32 [BT,3,96,96] ============
// per 16-px tile: C[16 px][16 n] = im2col_A[16][576] * w4c^T; n = cls*3+oc (12 used)
// k = (dh*3+dw)*64 + ic over the 3x3 input neighborhood; w4c has structural zeros.
__global__ __launch_bounds__(256) void deconv4_kernel(
    const unsigned short* __restrict__ act3p, const unsigned short* __restrict__ w4c,
    const float* __restrict__ b4, float* __restrict__ out) {
  int tid = threadIdx.x;
  int wave = tid >> 6, lane = tid & 63, quad = lane >> 4, l16 = lane & 15;
  int bt = blockIdx.y;
  int tile = blockIdx.x * 4 + wave;  // 0..143; 48/16=3 tiles per row (no row crossing)
  int i = tile / 3, j0 = (tile - i * 3) * 16;
  const unsigned short* abase =
      act3p + (size_t)bt * 160000u + (size_t)((i * 50) + (j0 + l16)) * 64;
  const unsigned short* bbase = w4c + l16 * 576 + quad * 8;

  floatx4 acc = (floatx4){0.f, 0.f, 0.f, 0.f};
#pragma unroll
  for (int kk = 0; kk < 18; kk++) {
    int t = kk >> 1;
    int dh = t / 3, dw = t - dh * 3;
    int icq = (kk & 1) * 32 + quad * 8;
    UV a, b;
    a.u = *(const uint4*)(abase + (dh * 50 + dw) * 64 + icq);
    b.u = *(const uint4*)(bbase + kk * 32);
    acc = __builtin_amdgcn_mfma_f32_16x16x32_bf16(a.s, b.s, acc, 0, 0, 0);
  }

  int n = l16;
  if (n < 12) {
    int cls = n / 3, oc = n - cls * 3;
    int r = cls >> 1, s = cls & 1;
    float bias = b4[oc];
    int oh = 2 * i + r;
    float* obase = out + (size_t)bt * 27648u + oc * 9216 + oh * 96 + s;
#pragma unroll
    for (int reg = 0; reg < 4; reg++) {
      int jj = j0 + quad * 4 + reg;
      obase[2 * jj] = ftanh(acc[reg] + bias);
    }
  }
}

extern "C" void kernel_launch(void* const* d_in, const int* in_sizes, int n_in,
                              void* d_out, int out_size, void* d_ws, size_t ws_size,
                              hipStream_t stream) {
  const float* ident = (const float*)d_in[0];
  const float* lm = (const float*)d_in[1];
  const float* w1 = (const float*)d_in[2];
  const float* b1 = (const float*)d_in[3];
  const float* w2 = (const float*)d_in[4];
  const float* b2 = (const float*)d_in[5];
  const float* w3 = (const float*)d_in[6];
  const float* b3 = (const float*)d_in[7];
  const float* w4 = (const float*)d_in[8];
  const float* b4 = (const float*)d_in[9];
  float* out = (float*)d_out;
  char* ws = (char*)d_ws;
  unsigned short* identp = (unsigned short*)(ws + IDENTP_OFF);
  unsigned short* hmp = (unsigned short*)(ws + HMP_OFF);
  unsigned short* act1p = (unsigned short*)(ws + ACT1P_OFF);
  unsigned short* act2p = (unsigned short*)(ws + ACT2P_OFF);
  unsigned short* act3p = (unsigned short*)(ws + ACT3P_OFF);
  unsigned short* w2a = (unsigned short*)(ws + W2A_OFF);
  unsigned short* w3a = (unsigned short*)(ws + W3A_OFF);
  unsigned short* w1b = (unsigned short*)(ws + W1B_OFF);
  unsigned short* w4c = (unsigned short*)(ws + W4C_OFF);

  prep_kernel<<<dim3(922), 256, 0, stream>>>(lm, ident, w1, w2, w3, w4, identp, hmp,
                                             w1b, w2a, w3a, w4c, act1p, act2p);
  conv1_kernel<<<dim3(36, 256), 256, 0, stream>>>(identp, hmp, w1b, b1, act1p);
  conv2_kernel<<<dim3(9, 256), 256, 0, stream>>>(act1p, w2a, b2, act2p);
  deconv3_kernel<<<dim3(9, 2, 256), 256, 0, stream>>>(act2p, w3a, b3, act3p);
  deconv4_kernel<<<dim3(36, 256), 256, 0, stream>>>(act3p, w4c, b4, out);
}

// Round 6
// 441.633 us; speedup vs baseline: 1.1544x; 1.1544x over previous
//
#include <hip/hip_runtime.h>

// ---- workspace layout (bytes) ----
#define IDENTP_OFF 0u            // identp: 8*3*98*100*2 = 470400
#define HMP_OFF    470400u       // hmp: 256*98*100*2 = 5017600
#define ACT1CL_OFF 5488000u      // act1cl: 256*50*52*64*2 = 85196800 (ends 90684800)
#define ACT3P_OFF  470400u       // act3p: 256*50*50*64*2 = 81920000 — aliases hmp+act1cl (dead after conv2)
#define ACT2P_OFF  90684800u     // act2p: 256*26*26*128*2 = 44302336
#define W2B_OFF    134987136u    // w2b: 128*1024*2 = 262144
#define W3B_OFF    135249280u    // w3b: 2*128*768*2 = 393216
#define W1B_OFF    135642496u    // w1b: 64*64*2 = 8192
#define W4C_OFF    135650688u    // w4c: 16*576*2 = 18432

using short8  = __attribute__((ext_vector_type(8))) short;
using floatx4 = __attribute__((ext_vector_type(4))) float;
union UV { uint4 u; short8 s; };

static __device__ __forceinline__ float bf2f(unsigned short u) {
  union { unsigned int i; float f; } v; v.i = ((unsigned int)u) << 16; return v.f;
}
static __device__ __forceinline__ unsigned short f2bf(float f) {
  union { float f; unsigned int i; } v; v.f = f;
  unsigned int x = v.i;
  return (unsigned short)((x + 0x7FFFu + ((x >> 16) & 1u)) >> 16);  // RNE
}
static __device__ __forceinline__ uint4 pack8(const unsigned short* v) {
  uint4 p;
  p.x = (unsigned)v[0] | ((unsigned)v[1] << 16);
  p.y = (unsigned)v[2] | ((unsigned)v[3] << 16);
  p.z = (unsigned)v[4] | ((unsigned)v[5] << 16);
  p.w = (unsigned)v[6] | ((unsigned)v[7] << 16);
  return p;
}
static __device__ __forceinline__ float ftanh(float x) {
  x = fminf(fmaxf(x, -10.f), 10.f);
  float e = __expf(2.f * x);
  return (e - 1.f) * __builtin_amdgcn_rcpf(e + 1.f);
}

// ============ prep ============
__global__ __launch_bounds__(256) void prep_kernel(
    const float* __restrict__ lm, const float* __restrict__ ident,
    const float* __restrict__ w1, const float* __restrict__ w2,
    const float* __restrict__ w3, const float* __restrict__ w4,
    unsigned short* __restrict__ identp, unsigned short* __restrict__ hmp,
    unsigned short* __restrict__ w1b, unsigned short* __restrict__ w2b,
    unsigned short* __restrict__ w3b, unsigned short* __restrict__ w4c,
    unsigned short* __restrict__ act1cl, unsigned short* __restrict__ act2p) {
  int bid = blockIdx.x, tid = threadIdx.x;
  if (bid < 256) {
    // hmp [bt][98][100]
    unsigned int* h32 = (unsigned int*)(hmp + bid * 9800);
    for (int i = tid; i < 4900; i += 256) h32[i] = 0u;
    __syncthreads();
    if (tid < 68) {
      float x = lm[bid * 136 + tid * 2 + 0] * 95.0f;
      float y = lm[bid * 136 + tid * 2 + 1] * 95.0f;
      int ix = (int)x, iy = (int)y;
      if (ix >= 0 && ix < 96 && iy >= 0 && iy < 96)
        hmp[bid * 9800 + (iy + 1) * 100 + (ix + 1)] = 0x3F80;
    }
  } else if (bid < 320) {
    // w2b [oc128][k'1024], k' = (kh*4+kw)*64 + ic ; w2 native k = ic*16+kh*4+kw
    int e = (bid - 256) * 2048 + tid * 8;
    int oc = e >> 10, kp = e & 1023;
    int tap = kp >> 6, ic0 = kp & 63;
    unsigned short v[8];
#pragma unroll
    for (int j = 0; j < 8; j++) v[j] = f2bf(w2[oc * 1024 + (ic0 + j) * 16 + tap]);
    *(uint4*)(w2b + e) = pack8(v);
  } else if (bid < 416) {
    // w3b [r2][n128][k768]: n=s*64+oc, k=(dh*3+dw)*128+ic; a=1-dh, b=s+1-dw
    int idx = (bid - 320) * 2048 + tid * 8;
    int r = idx / 98304;
    int rem = idx - r * 98304;
    int n = rem / 768, k = rem - n * 768;
    int s = n >> 6, oc = n & 63;
    int tap = k >> 7, ic0 = k & 127;
    int dh = tap / 3, dw = tap - dh * 3;
    int a = 1 - dh, bb = s + 1 - dw;
    unsigned short v[8];
    if (bb >= 0 && bb <= 1) {
      int kh = 2 * a + 1 - r, kw = 2 * bb + 1 - s;
#pragma unroll
      for (int j = 0; j < 8; j++)
        v[j] = f2bf(w3[((ic0 + j) * 64 + oc) * 16 + kh * 4 + kw]);
    } else {
#pragma unroll
      for (int j = 0; j < 8; j++) v[j] = 0;
    }
    *(uint4*)(w3b + idx) = pack8(v);
  } else if (bid < 440) {
    // identp [b*3+ic][98][100]
    int bci = bid - 416;
    const float* src = ident + bci * 9216;
    unsigned short* dst = identp + bci * 9800;
    for (int i = tid; i < 9800; i += 256) {
      int row = i / 100, col = i - row * 100;
      bool in = (row >= 1) && (row <= 96) && (col >= 1) && (col <= 96);
      dst[i] = in ? f2bf(src[(row - 1) * 96 + (col - 1)]) : (unsigned short)0;
    }
  } else if (bid < 696) {
    // act1cl halo zero [50][52][64]: rows 0,49 (cols 0..49) + cols 0,49 (rows 1..48)
    unsigned short* base = act1cl + (size_t)(bid - 440) * 166400u;
    for (int c = tid; c < 1568; c += 256) {
      int cell = c >> 3, v = c & 7;
      int row, col;
      if (cell < 50) { row = 0; col = cell; }
      else if (cell < 100) { row = 49; col = cell - 50; }
      else if (cell < 148) { row = cell - 99; col = 0; }
      else { row = cell - 147; col = 49; }
      *(uint4*)(base + (row * 52 + col) * 64 + v * 8) = (uint4){0, 0, 0, 0};
    }
  } else if (bid < 952) {
    // act2p halo zero [26][26][128]
    uint4* b4p = (uint4*)(act2p + (size_t)(bid - 696) * 86528u);
    uint4 z = {0, 0, 0, 0};
    for (int c = tid; c < 1600; c += 256) {
      int cell = c >> 4, v = c & 15;
      int row, col;
      if (cell < 26) { row = 0; col = cell; }
      else if (cell < 52) { row = 25; col = cell - 26; }
      else if (cell < 76) { row = cell - 51; col = 0; }
      else { row = cell - 75; col = 25; }
      b4p[(row * 26 + col) * 16 + v] = z;
    }
  } else if (bid == 952) {
    // w1b [64 oc][64 k native]
    int e = tid * 16;
    unsigned short v[16];
#pragma unroll
    for (int q = 0; q < 4; q++) {
      float4 f = *(const float4*)(w1 + e + q * 4);
      v[q * 4 + 0] = f2bf(f.x); v[q * 4 + 1] = f2bf(f.y);
      v[q * 4 + 2] = f2bf(f.z); v[q * 4 + 3] = f2bf(f.w);
    }
    *(uint4*)(w1b + e) = pack8(v);
    *(uint4*)(w1b + e + 8) = pack8(v + 8);
  } else {
    // w4c [n16][k576]: k=(dh*3+dw)*64+ic; n=cls*3+oc
    for (int idx = tid; idx < 9216; idx += 256) {
      int n = idx / 576, k = idx - n * 576;
      int t = k >> 6, ic = k & 63;
      int dh = t / 3, dw = t - dh * 3;
      unsigned short val = 0;
      if (n < 12) {
        int cls = n / 3, oc = n - cls * 3;
        int r = cls >> 1, s = cls & 1;
        int a = r - dh + 1, b = s - dw + 1;
        if (a >= 0 && a < 2 && b >= 0 && b < 2) {
          int kh = 2 * a + 1 - r, kw = 2 * b + 1 - s;
          val = f2bf(w4[ic * 48 + oc * 16 + kh * 4 + kw]);
        }
      }
      w4c[idx] = val;
    }
  }
}

// ============ conv1 (MFMA, role-swapped): -> act1cl [50][52][64] ============
// per wave: C[16 px][64 oc]; A im2col direct global, B = w1b direct (L1-hot)
__global__ __launch_bounds__(256) void conv1_kernel(
    const unsigned short* __restrict__ identp, const unsigned short* __restrict__ hmp,
    const unsigned short* __restrict__ w1b, const float* __restrict__ b1,
    unsigned short* __restrict__ act1cl) {
  __shared__ unsigned short stage[4608];  // 4 waves x 16 px x 72
  int tid = threadIdx.x;
  int bx = blockIdx.x, bt = blockIdx.y;
  int b = bt >> 5;
  int wave = tid >> 6, lane = tid & 63, quad = lane >> 4, l16 = lane & 15;
  int px0 = bx * 64 + wave * 16;
  int pxa = px0 + l16;
  int oh = pxa / 48, ow = pxa % 48;

  floatx4 acc[4];
#pragma unroll
  for (int nt = 0; nt < 4; nt++) acc[nt] = (floatx4){0.f, 0.f, 0.f, 0.f};

#pragma unroll
  for (int kk = 0; kk < 2; kk++) {
    int k0 = kk * 32 + quad * 8;
    int ic = k0 >> 4, khp = (k0 >> 3) & 1;
    const unsigned short* src = (ic < 3) ? identp + (b * 3 + ic) * 9800
                                         : hmp + bt * 9800;
    const unsigned short* p = src + (2 * oh + khp * 2) * 100 + 2 * ow;
    UV a;
    a.u.x = *(const unsigned int*)(p);
    a.u.y = *(const unsigned int*)(p + 2);
    a.u.z = *(const unsigned int*)(p + 100);
    a.u.w = *(const unsigned int*)(p + 102);
#pragma unroll
    for (int nt = 0; nt < 4; nt++) {
      UV bv;
      bv.u = *(const uint4*)(w1b + (nt * 16 + l16) * 64 + kk * 32 + quad * 8);
      acc[nt] = __builtin_amdgcn_mfma_f32_16x16x32_bf16(a.s, bv.s, acc[nt], 0, 0, 0);
    }
  }

  float bias[4];
#pragma unroll
  for (int nt = 0; nt < 4; nt++) bias[nt] = b1[nt * 16 + l16];
  unsigned short* sw = stage + wave * 1152;
#pragma unroll
  for (int nt = 0; nt < 4; nt++)
#pragma unroll
    for (int reg = 0; reg < 4; reg++) {
      float v = fmaxf(acc[nt][reg] + bias[nt], 0.f);
      sw[(quad * 4 + reg) * 72 + nt * 16 + l16] = f2bf(v);
    }
  __syncthreads();
  // store: 16 px x 128B contiguous records
  int oh0 = px0 / 48, ow0 = px0 % 48;
  unsigned short* gout = act1cl + (size_t)bt * 166400u + ((oh0 + 1) * 52 + ow0 + 1) * 64;
#pragma unroll
  for (int it = 0; it < 8; it++) {
    int pl = it * 2 + (lane >> 5);
    unsigned int v = *(const unsigned int*)(sw + pl * 72 + (lane & 31) * 2);
    *(unsigned int*)(gout + pl * 64 + (lane & 31) * 2) = v;
  }
}

// ============ conv2 (MFMA, role-swapped): act1cl -> relu -> act2p [26][26][128] ============
// per wave: C[48 px][128 oc]; A direct global dwordx4; B (w2b) LDS ping-pong
__global__ __launch_bounds__(256, 2) void conv2_kernel(
    const unsigned short* __restrict__ act1cl, const unsigned short* __restrict__ w2b,
    const float* __restrict__ b2, unsigned short* __restrict__ act2p) {
  __shared__ unsigned short Blds[2][128 * 40];  // 20480 B
  int tid = threadIdx.x;
  int bx = blockIdx.x, bt = blockIdx.y;
  int wave = tid >> 6, lane = tid & 63, quad = lane >> 4, l16 = lane & 15;
  const unsigned short* frame = act1cl + (size_t)bt * 166400u;
  const unsigned short* abase[3];
#pragma unroll
  for (int mf = 0; mf < 3; mf++) {
    int px = bx * 192 + wave * 48 + mf * 16 + l16;
    int oh = px / 24, ow = px % 24;
    abase[mf] = frame + ((2 * oh) * 52 + 2 * ow) * 64 + quad * 8;
  }
  int sn = tid >> 1, spart = tid & 1;
  const unsigned short* bptr = w2b + sn * 1024 + spart * 16;
  unsigned short* sdst = &Blds[0][0] + sn * 40 + spart * 16;

  floatx4 acc[3][8];
#pragma unroll
  for (int mf = 0; mf < 3; mf++)
#pragma unroll
    for (int nt = 0; nt < 8; nt++) acc[mf][nt] = (floatx4){0.f, 0.f, 0.f, 0.f};

  // prologue
  {
    uint4 s0 = *(const uint4*)(bptr);
    uint4 s1 = *(const uint4*)(bptr + 8);
    *(uint4*)(sdst) = s0;
    *(uint4*)(sdst + 8) = s1;
  }
  UV a_cur[3], a_nxt[3];
#pragma unroll
  for (int mf = 0; mf < 3; mf++) a_cur[mf].u = *(const uint4*)(abase[mf]);
  __syncthreads();

#pragma unroll 2
  for (int kk = 0; kk < 32; kk++) {
    int cur = kk & 1;
    UV bf[8];
#pragma unroll
    for (int nt = 0; nt < 8; nt++)
      bf[nt].u = *(const uint4*)(&Blds[cur][(nt * 16 + l16) * 40 + quad * 8]);
    uint4 ns0, ns1;
    if (kk < 31) {
      int kn = (kk + 1) * 32;
      ns0 = *(const uint4*)(bptr + kn);
      ns1 = *(const uint4*)(bptr + kn + 8);
      int tap = (kk + 1) >> 1, ic0 = ((kk + 1) & 1) * 32;
      int kh = tap >> 2, kw = tap & 3;
      int aoff = (kh * 52 + kw) * 64 + ic0;
#pragma unroll
      for (int mf = 0; mf < 3; mf++) a_nxt[mf].u = *(const uint4*)(abase[mf] + aoff);
    }
#pragma unroll
    for (int mf = 0; mf < 3; mf++)
#pragma unroll
      for (int nt = 0; nt < 8; nt++)
        acc[mf][nt] = __builtin_amdgcn_mfma_f32_16x16x32_bf16(a_cur[mf].s, bf[nt].s, acc[mf][nt], 0, 0, 0);
    if (kk < 31) {
      unsigned short* d = sdst + (1 - cur) * 5120;
      *(uint4*)(d) = ns0;
      *(uint4*)(d + 8) = ns1;
    }
    __syncthreads();
#pragma unroll
    for (int mf = 0; mf < 3; mf++) a_cur[mf] = a_nxt[mf];
  }

  float bias[8];
#pragma unroll
  for (int nt = 0; nt < 8; nt++) bias[nt] = b2[nt * 16 + l16];
  unsigned short* sw = &Blds[0][0] + wave * 2176;  // 16 px x 136
  unsigned short* obase = act2p + (size_t)bt * 86528u;
#pragma unroll
  for (int mf = 0; mf < 3; mf++) {
#pragma unroll
    for (int nt = 0; nt < 8; nt++)
#pragma unroll
      for (int reg = 0; reg < 4; reg++) {
        float v = fmaxf(acc[mf][nt][reg] + bias[nt], 0.f);
        sw[(quad * 4 + reg) * 136 + nt * 16 + l16] = f2bf(v);
      }
    __syncthreads();
#pragma unroll
    for (int it = 0; it < 16; it++) {
      unsigned int v = *(const unsigned int*)(sw + it * 136 + lane * 2);
      int px = bx * 192 + wave * 48 + mf * 16 + it;
      int oh = px / 24, ow = px % 24;
      *(unsigned int*)(obase + ((oh + 1) * 26 + ow + 1) * 128 + lane * 2) = v;
    }
    __syncthreads();
  }
}

// ============ deconv3 (MFMA, role-swapped): act2p -> relu -> act3p [50][50][64] ============
// per (frame, r): C[576 px][128 n], n = s*64+oc; K=768 (2x3 neighborhood, 1/3 zeros)
__global__ __launch_bounds__(256, 2) void deconv3_kernel(
    const unsigned short* __restrict__ act2p, const unsigned short* __restrict__ w3b,
    const float* __restrict__ b3, unsigned short* __restrict__ act3p) {
  __shared__ unsigned short Blds[2][128 * 40];
  int tid = threadIdx.x;
  int bx = blockIdx.x, r = blockIdx.y, bt = blockIdx.z;
  int wave = tid >> 6, lane = tid & 63, quad = lane >> 4, l16 = lane & 15;
  const unsigned short* a2 = act2p + (size_t)bt * 86528u;
  unsigned short* a3 = act3p + (size_t)bt * 160000u;

  // halo zero (one block per frame)
  if (bx == 0 && r == 0) {
    uint4* hz = (uint4*)a3;
    uint4 z = {0, 0, 0, 0};
    for (int c = tid; c < 1568; c += 256) {
      int cell = c >> 3, v = c & 7;
      int row, col;
      if (cell < 50) { row = 0; col = cell; }
      else if (cell < 100) { row = 49; col = cell - 50; }
      else if (cell < 148) { row = cell - 99; col = 0; }
      else { row = cell - 147; col = 49; }
      hz[(row * 50 + col) * 8 + v] = z;
    }
  }

  const unsigned short* abase[3];
#pragma unroll
  for (int mf = 0; mf < 3; mf++) {
    int px = bx * 192 + wave * 48 + mf * 16 + l16;
    int i = px / 24, j = px % 24;
    abase[mf] = a2 + ((i + r) * 26 + j) * 128 + quad * 8;
  }
  int sn = tid >> 1, spart = tid & 1;
  const unsigned short* bptr = w3b + r * 98304 + sn * 768 + spart * 16;
  unsigned short* sdst = &Blds[0][0] + sn * 40 + spart * 16;

  floatx4 acc[3][8];
#pragma unroll
  for (int mf = 0; mf < 3; mf++)
#pragma unroll
    for (int nt = 0; nt < 8; nt++) acc[mf][nt] = (floatx4){0.f, 0.f, 0.f, 0.f};

  {
    uint4 s0 = *(const uint4*)(bptr);
    uint4 s1 = *(const uint4*)(bptr + 8);
    *(uint4*)(sdst) = s0;
    *(uint4*)(sdst + 8) = s1;
  }
  UV a_cur[3], a_nxt[3];
#pragma unroll
  for (int mf = 0; mf < 3; mf++) a_cur[mf].u = *(const uint4*)(abase[mf]);
  __syncthreads();

#pragma unroll 2
  for (int kk = 0; kk < 24; kk++) {
    int cur = kk & 1;
    UV bf[8];
#pragma unroll
    for (int nt = 0; nt < 8; nt++)
      bf[nt].u = *(const uint4*)(&Blds[cur][(nt * 16 + l16) * 40 + quad * 8]);
    uint4 ns0, ns1;
    if (kk < 23) {
      int kn = (kk + 1) * 32;
      ns0 = *(const uint4*)(bptr + kn);
      ns1 = *(const uint4*)(bptr + kn + 8);
      int tap = (kk + 1) >> 2, ic0 = ((kk + 1) & 3) * 32;
      int dh = tap / 3, dw = tap - dh * 3;
      int aoff = (dh * 26 + dw) * 128 + ic0;
#pragma unroll
      for (int mf = 0; mf < 3; mf++) a_nxt[mf].u = *(const uint4*)(abase[mf] + aoff);
    }
#pragma unroll
    for (int mf = 0; mf < 3; mf++)
#pragma unroll
      for (int nt = 0; nt < 8; nt++)
        acc[mf][nt] = __builtin_amdgcn_mfma_f32_16x16x32_bf16(a_cur[mf].s, bf[nt].s, acc[mf][nt], 0, 0, 0);
    if (kk < 23) {
      unsigned short* d = sdst + (1 - cur) * 5120;
      *(uint4*)(d) = ns0;
      *(uint4*)(d + 8) = ns1;
    }
    __syncthreads();
#pragma unroll
    for (int mf = 0; mf < 3; mf++) a_cur[mf] = a_nxt[mf];
  }

  float bias[8];
#pragma unroll
  for (int nt = 0; nt < 8; nt++) bias[nt] = b3[(nt * 16 + l16) & 63];
  unsigned short* sw = &Blds[0][0] + wave * 2176;
#pragma unroll
  for (int mf = 0; mf < 3; mf++) {
#pragma unroll
    for (int nt = 0; nt < 8; nt++)
#pragma unroll
      for (int reg = 0; reg < 4; reg++) {
        float v = fmaxf(acc[mf][nt][reg] + bias[nt], 0.f);
        sw[(quad * 4 + reg) * 136 + nt * 16 + l16] = f2bf(v);
      }
    __syncthreads();
#pragma unroll
    for (int it = 0; it < 16; it++) {
      unsigned int v = *(const unsigned int*)(sw + it * 136 + lane * 2);
      int px = bx * 192 + wave * 48 + mf * 16 + it;
      int i = px / 24, j = px % 24;
      *(unsigned int*)(a3 + ((2 * i + r + 1) * 50 + 2 * j + 1) * 64 + lane * 2) = v;
    }
    __syncthreads();
  }
}

// ============ deconv4 (MFMA, LDS-free) + tanh: act3p -> out fp32 [BT,3,96,96] ============
__global__ __launch_bounds__(256) void deconv4_kernel(
    const unsigned short* __restrict__ act3p, const unsigned short* __restrict__ w4c,
    const float* __restrict__ b4, float* __restrict__ out) {
  int tid = threadIdx.x;
  int wave = tid >> 6, lane = tid & 63, quad = lane >> 4, l16 = lane & 15;
  int bt = blockIdx.y;
  int tile = blockIdx.x * 4 + wave;
  int i = tile / 3, j0 = (tile - i * 3) * 16;
  const unsigned short* abase =
      act3p + (size_t)bt * 160000u + (size_t)((i * 50) + (j0 + l16)) * 64;
  const unsigned short* bbase = w4c + l16 * 576 + quad * 8;

  floatx4 acc = (floatx4){0.f, 0.f, 0.f, 0.f};
#pragma unroll
  for (int kk = 0; kk < 18; kk++) {
    int t = kk >> 1;
    int dh = t / 3, dw = t - dh * 3;
    int icq = (kk & 1) * 32 + quad * 8;
    UV a, b;
    a.u = *(const uint4*)(abase + (dh * 50 + dw) * 64 + icq);
    b.u = *(const uint4*)(bbase + kk * 32);
    acc = __builtin_amdgcn_mfma_f32_16x16x32_bf16(a.s, b.s, acc, 0, 0, 0);
  }

  int n = l16;
  if (n < 12) {
    int cls = n / 3, oc = n - cls * 3;
    int r = cls >> 1, s = cls & 1;
    float bias = b4[oc];
    int oh = 2 * i + r;
    float* obase = out + (size_t)bt * 27648u + oc * 9216 + oh * 96 + s;
#pragma unroll
    for (int reg = 0; reg < 4; reg++) {
      int jj = j0 + quad * 4 + reg;
      obase[2 * jj] = ftanh(acc[reg] + bias);
    }
  }
}

extern "C" void kernel_launch(void* const* d_in, const int* in_sizes, int n_in,
                              void* d_out, int out_size, void* d_ws, size_t ws_size,
                              hipStream_t stream) {
  const float* ident = (const float*)d_in[0];
  const float* lm = (const float*)d_in[1];
  const float* w1 = (const float*)d_in[2];
  const float* b1 = (const float*)d_in[3];
  const float* w2 = (const float*)d_in[4];
  const float* b2 = (const float*)d_in[5];
  const float* w3 = (const float*)d_in[6];
  const float* b3 = (const float*)d_in[7];
  const float* w4 = (const float*)d_in[8];
  const float* b4 = (const float*)d_in[9];
  float* out = (float*)d_out;
  char* ws = (char*)d_ws;
  unsigned short* identp = (unsigned short*)(ws + IDENTP_OFF);
  unsigned short* hmp = (unsigned short*)(ws + HMP_OFF);
  unsigned short* act1cl = (unsigned short*)(ws + ACT1CL_OFF);
  unsigned short* act2p = (unsigned short*)(ws + ACT2P_OFF);
  unsigned short* act3p = (unsigned short*)(ws + ACT3P_OFF);
  unsigned short* w2b = (unsigned short*)(ws + W2B_OFF);
  unsigned short* w3b = (unsigned short*)(ws + W3B_OFF);
  unsigned short* w1b = (unsigned short*)(ws + W1B_OFF);
  unsigned short* w4c = (unsigned short*)(ws + W4C_OFF);

  prep_kernel<<<dim3(954), 256, 0, stream>>>(lm, ident, w1, w2, w3, w4, identp, hmp,
                                             w1b, w2b, w3b, w4c, act1cl, act2p);
  conv1_kernel<<<dim3(36, 256), 256, 0, stream>>>(identp, hmp, w1b, b1, act1cl);
  conv2_kernel<<<dim3(3, 256), 256, 0, stream>>>(act1cl, w2b, b2, act2p);
  deconv3_kernel<<<dim3(3, 2, 256), 256, 0, stream>>>(act2p, w3b, b3, act3p);
  deconv4_kernel<<<dim3(36, 256), 256, 0, stream>>>(act3p, w4c, b4, out);
}

// Round 7
// 440.624 us; speedup vs baseline: 1.1570x; 1.0023x over previous
//
#include <hip/hip_runtime.h>

// ---- workspace layout (bytes) ----
#define IDENTP_OFF 0u            // identp: 8*3*98*100*2 = 470400
#define HMP_OFF    470400u       // hmp: 256*98*100*2 = 5017600
#define ACT1CL_OFF 5488000u      // act1cl: 256*50*52*64*2 = 85196800 (ends 90684800)
#define ACT3P_OFF  470400u       // act3p: 256*50*50*64*2 = 81920000 — aliases hmp+act1cl (dead after conv2)
#define ACT2P_OFF  90684800u     // act2p: 256*26*26*128*2 = 44302336
#define W2B_OFF    134987136u    // w2b: 128*1024*2 = 262144
#define W3B_OFF    135249280u    // w3b: 2*128*768*2 = 393216
#define W1B_OFF    135642496u    // w1b: 64*64*2 = 8192
#define W4C_OFF    135650688u    // w4c: 16*576*2 = 18432

using short8  = __attribute__((ext_vector_type(8))) short;
using floatx4 = __attribute__((ext_vector_type(4))) float;
union UV { uint4 u; short8 s; };

static __device__ __forceinline__ float bf2f(unsigned short u) {
  union { unsigned int i; float f; } v; v.i = ((unsigned int)u) << 16; return v.f;
}
static __device__ __forceinline__ unsigned short f2bf(float f) {
  union { float f; unsigned int i; } v; v.f = f;
  unsigned int x = v.i;
  return (unsigned short)((x + 0x7FFFu + ((x >> 16) & 1u)) >> 16);  // RNE
}
static __device__ __forceinline__ uint4 pack8(const unsigned short* v) {
  uint4 p;
  p.x = (unsigned)v[0] | ((unsigned)v[1] << 16);
  p.y = (unsigned)v[2] | ((unsigned)v[3] << 16);
  p.z = (unsigned)v[4] | ((unsigned)v[5] << 16);
  p.w = (unsigned)v[6] | ((unsigned)v[7] << 16);
  return p;
}
static __device__ __forceinline__ float ftanh(float x) {
  x = fminf(fmaxf(x, -10.f), 10.f);
  float e = __expf(2.f * x);
  return (e - 1.f) * __builtin_amdgcn_rcpf(e + 1.f);
}

// ============ prep ============
__global__ __launch_bounds__(256) void prep_kernel(
    const float* __restrict__ lm, const float* __restrict__ ident,
    const float* __restrict__ w1, const float* __restrict__ w2,
    const float* __restrict__ w3, const float* __restrict__ w4,
    unsigned short* __restrict__ identp, unsigned short* __restrict__ hmp,
    unsigned short* __restrict__ w1b, unsigned short* __restrict__ w2b,
    unsigned short* __restrict__ w3b, unsigned short* __restrict__ w4c,
    unsigned short* __restrict__ act1cl, unsigned short* __restrict__ act2p) {
  int bid = blockIdx.x, tid = threadIdx.x;
  if (bid < 256) {
    // hmp [bt][98][100]
    unsigned int* h32 = (unsigned int*)(hmp + bid * 9800);
    for (int i = tid; i < 4900; i += 256) h32[i] = 0u;
    __syncthreads();
    if (tid < 68) {
      float x = lm[bid * 136 + tid * 2 + 0] * 95.0f;
      float y = lm[bid * 136 + tid * 2 + 1] * 95.0f;
      int ix = (int)x, iy = (int)y;
      if (ix >= 0 && ix < 96 && iy >= 0 && iy < 96)
        hmp[bid * 9800 + (iy + 1) * 100 + (ix + 1)] = 0x3F80;
    }
  } else if (bid < 320) {
    // w2b [oc128][k'1024], k' = (kh*4+kw)*64 + ic ; w2 native k = ic*16+kh*4+kw
    int e = (bid - 256) * 2048 + tid * 8;
    int oc = e >> 10, kp = e & 1023;
    int tap = kp >> 6, ic0 = kp & 63;
    unsigned short v[8];
#pragma unroll
    for (int j = 0; j < 8; j++) v[j] = f2bf(w2[oc * 1024 + (ic0 + j) * 16 + tap]);
    *(uint4*)(w2b + e) = pack8(v);
  } else if (bid < 416) {
    // w3b [r2][n128][k768]: n=s*64+oc, k=(dh*3+dw)*128+ic; a=1-dh, b=s+1-dw
    int idx = (bid - 320) * 2048 + tid * 8;
    int r = idx / 98304;
    int rem = idx - r * 98304;
    int n = rem / 768, k = rem - n * 768;
    int s = n >> 6, oc = n & 63;
    int tap = k >> 7, ic0 = k & 127;
    int dh = tap / 3, dw = tap - dh * 3;
    int a = 1 - dh, bb = s + 1 - dw;
    unsigned short v[8];
    if (bb >= 0 && bb <= 1) {
      int kh = 2 * a + 1 - r, kw = 2 * bb + 1 - s;
#pragma unroll
      for (int j = 0; j < 8; j++)
        v[j] = f2bf(w3[((ic0 + j) * 64 + oc) * 16 + kh * 4 + kw]);
    } else {
#pragma unroll
      for (int j = 0; j < 8; j++) v[j] = 0;
    }
    *(uint4*)(w3b + idx) = pack8(v);
  } else if (bid < 440) {
    // identp [b*3+ic][98][100]
    int bci = bid - 416;
    const float* src = ident + bci * 9216;
    unsigned short* dst = identp + bci * 9800;
    for (int i = tid; i < 9800; i += 256) {
      int row = i / 100, col = i - row * 100;
      bool in = (row >= 1) && (row <= 96) && (col >= 1) && (col <= 96);
      dst[i] = in ? f2bf(src[(row - 1) * 96 + (col - 1)]) : (unsigned short)0;
    }
  } else if (bid < 696) {
    // act1cl halo zero [50][52][64]
    unsigned short* base = act1cl + (size_t)(bid - 440) * 166400u;
    for (int c = tid; c < 1568; c += 256) {
      int cell = c >> 3, v = c & 7;
      int row, col;
      if (cell < 50) { row = 0; col = cell; }
      else if (cell < 100) { row = 49; col = cell - 50; }
      else if (cell < 148) { row = cell - 99; col = 0; }
      else { row = cell - 147; col = 49; }
      *(uint4*)(base + (row * 52 + col) * 64 + v * 8) = (uint4){0, 0, 0, 0};
    }
  } else if (bid < 952) {
    // act2p halo zero [26][26][128]
    uint4* b4p = (uint4*)(act2p + (size_t)(bid - 696) * 86528u);
    uint4 z = {0, 0, 0, 0};
    for (int c = tid; c < 1600; c += 256) {
      int cell = c >> 4, v = c & 15;
      int row, col;
      if (cell < 26) { row = 0; col = cell; }
      else if (cell < 52) { row = 25; col = cell - 26; }
      else if (cell < 76) { row = cell - 51; col = 0; }
      else { row = cell - 75; col = 25; }
      b4p[(row * 26 + col) * 16 + v] = z;
    }
  } else if (bid == 952) {
    // w1b [64 oc][64 k native]
    int e = tid * 16;
    unsigned short v[16];
#pragma unroll
    for (int q = 0; q < 4; q++) {
      float4 f = *(const float4*)(w1 + e + q * 4);
      v[q * 4 + 0] = f2bf(f.x); v[q * 4 + 1] = f2bf(f.y);
      v[q * 4 + 2] = f2bf(f.z); v[q * 4 + 3] = f2bf(f.w);
    }
    *(uint4*)(w1b + e) = pack8(v);
    *(uint4*)(w1b + e + 8) = pack8(v + 8);
  } else {
    // w4c [n16][k576]: k=(dh*3+dw)*64+ic; n=cls*3+oc
    for (int idx = tid; idx < 9216; idx += 256) {
      int n = idx / 576, k = idx - n * 576;
      int t = k >> 6, ic = k & 63;
      int dh = t / 3, dw = t - dh * 3;
      unsigned short val = 0;
      if (n < 12) {
        int cls = n / 3, oc = n - cls * 3;
        int r = cls >> 1, s = cls & 1;
        int a = r - dh + 1, b = s - dw + 1;
        if (a >= 0 && a < 2 && b >= 0 && b < 2) {
          int kh = 2 * a + 1 - r, kw = 2 * b + 1 - s;
          val = f2bf(w4[ic * 48 + oc * 16 + kh * 4 + kw]);
        }
      }
      w4c[idx] = val;
    }
  }
}

// ============ conv1 (MFMA, role-swapped): -> act1cl [50][52][64] ============
__global__ __launch_bounds__(256) void conv1_kernel(
    const unsigned short* __restrict__ identp, const unsigned short* __restrict__ hmp,
    const unsigned short* __restrict__ w1b, const float* __restrict__ b1,
    unsigned short* __restrict__ act1cl) {
  __shared__ unsigned short stage[4608];  // 4 waves x 16 px x 72
  int tid = threadIdx.x;
  int bx = blockIdx.x, bt = blockIdx.y;
  int b = bt >> 5;
  int wave = tid >> 6, lane = tid & 63, quad = lane >> 4, l16 = lane & 15;
  int px0 = bx * 64 + wave * 16;
  int pxa = px0 + l16;
  int oh = pxa / 48, ow = pxa % 48;

  floatx4 acc[4];
#pragma unroll
  for (int nt = 0; nt < 4; nt++) acc[nt] = (floatx4){0.f, 0.f, 0.f, 0.f};

#pragma unroll
  for (int kk = 0; kk < 2; kk++) {
    int k0 = kk * 32 + quad * 8;
    int ic = k0 >> 4, khp = (k0 >> 3) & 1;
    const unsigned short* src = (ic < 3) ? identp + (b * 3 + ic) * 9800
                                         : hmp + bt * 9800;
    const unsigned short* p = src + (2 * oh + khp * 2) * 100 + 2 * ow;
    UV a;
    a.u.x = *(const unsigned int*)(p);
    a.u.y = *(const unsigned int*)(p + 2);
    a.u.z = *(const unsigned int*)(p + 100);
    a.u.w = *(const unsigned int*)(p + 102);
#pragma unroll
    for (int nt = 0; nt < 4; nt++) {
      UV bv;
      bv.u = *(const uint4*)(w1b + (nt * 16 + l16) * 64 + kk * 32 + quad * 8);
      acc[nt] = __builtin_amdgcn_mfma_f32_16x16x32_bf16(a.s, bv.s, acc[nt], 0, 0, 0);
    }
  }

  float bias[4];
#pragma unroll
  for (int nt = 0; nt < 4; nt++) bias[nt] = b1[nt * 16 + l16];
  unsigned short* sw = stage + wave * 1152;
#pragma unroll
  for (int nt = 0; nt < 4; nt++)
#pragma unroll
    for (int reg = 0; reg < 4; reg++) {
      float v = fmaxf(acc[nt][reg] + bias[nt], 0.f);
      sw[(quad * 4 + reg) * 72 + nt * 16 + l16] = f2bf(v);
    }
  __syncthreads();
  int oh0 = px0 / 48, ow0 = px0 % 48;
  unsigned short* gout = act1cl + (size_t)bt * 166400u + ((oh0 + 1) * 52 + ow0 + 1) * 64;
#pragma unroll
  for (int it = 0; it < 8; it++) {
    int pl = it * 2 + (lane >> 5);
    unsigned int v = *(const unsigned int*)(sw + pl * 72 + (lane & 31) * 2);
    *(unsigned int*)(gout + pl * 64 + (lane & 31) * 2) = v;
  }
}

// ============ conv2 (MFMA, role-swapped): act1cl -> relu -> act2p [26][26][128] ============
__global__ __launch_bounds__(256, 2) void conv2_kernel(
    const unsigned short* __restrict__ act1cl, const unsigned short* __restrict__ w2b,
    const float* __restrict__ b2, unsigned short* __restrict__ act2p) {
  __shared__ unsigned short Blds[2][128 * 40];  // 20480 B
  int tid = threadIdx.x;
  int bx = blockIdx.x, bt = blockIdx.y;
  int wave = tid >> 6, lane = tid & 63, quad = lane >> 4, l16 = lane & 15;
  const unsigned short* frame = act1cl + (size_t)bt * 166400u;
  const unsigned short* abase[3];
#pragma unroll
  for (int mf = 0; mf < 3; mf++) {
    int px = bx * 192 + wave * 48 + mf * 16 + l16;
    int oh = px / 24, ow = px % 24;
    abase[mf] = frame + ((2 * oh) * 52 + 2 * ow) * 64 + quad * 8;
  }
  int sn = tid >> 1, spart = tid & 1;
  const unsigned short* bptr = w2b + sn * 1024 + spart * 16;
  unsigned short* sdst = &Blds[0][0] + sn * 40 + spart * 16;

  floatx4 acc[3][8];
#pragma unroll
  for (int mf = 0; mf < 3; mf++)
#pragma unroll
    for (int nt = 0; nt < 8; nt++) acc[mf][nt] = (floatx4){0.f, 0.f, 0.f, 0.f};

  {
    uint4 s0 = *(const uint4*)(bptr);
    uint4 s1 = *(const uint4*)(bptr + 8);
    *(uint4*)(sdst) = s0;
    *(uint4*)(sdst + 8) = s1;
  }
  UV a_cur[3], a_nxt[3];
#pragma unroll
  for (int mf = 0; mf < 3; mf++) a_cur[mf].u = *(const uint4*)(abase[mf]);
  __syncthreads();

#pragma unroll 2
  for (int kk = 0; kk < 32; kk++) {
    int cur = kk & 1;
    UV bf[8];
#pragma unroll
    for (int nt = 0; nt < 8; nt++)
      bf[nt].u = *(const uint4*)(&Blds[cur][(nt * 16 + l16) * 40 + quad * 8]);
    uint4 ns0, ns1;
    if (kk < 31) {
      int kn = (kk + 1) * 32;
      ns0 = *(const uint4*)(bptr + kn);
      ns1 = *(const uint4*)(bptr + kn + 8);
      int tap = (kk + 1) >> 1, ic0 = ((kk + 1) & 1) * 32;
      int kh = tap >> 2, kw = tap & 3;
      int aoff = (kh * 52 + kw) * 64 + ic0;
#pragma unroll
      for (int mf = 0; mf < 3; mf++) a_nxt[mf].u = *(const uint4*)(abase[mf] + aoff);
    }
#pragma unroll
    for (int mf = 0; mf < 3; mf++)
#pragma unroll
      for (int nt = 0; nt < 8; nt++)
        acc[mf][nt] = __builtin_amdgcn_mfma_f32_16x16x32_bf16(a_cur[mf].s, bf[nt].s, acc[mf][nt], 0, 0, 0);
    if (kk < 31) {
      unsigned short* d = sdst + (1 - cur) * 5120;
      *(uint4*)(d) = ns0;
      *(uint4*)(d + 8) = ns1;
    }
    __syncthreads();
#pragma unroll
    for (int mf = 0; mf < 3; mf++) a_cur[mf] = a_nxt[mf];
  }

  float bias[8];
#pragma unroll
  for (int nt = 0; nt < 8; nt++) bias[nt] = b2[nt * 16 + l16];
  unsigned short* sw = &Blds[0][0] + wave * 2176;  // 16 px x 136
  unsigned short* obase = act2p + (size_t)bt * 86528u;
#pragma unroll
  for (int mf = 0; mf < 3; mf++) {
#pragma unroll
    for (int nt = 0; nt < 8; nt++)
#pragma unroll
      for (int reg = 0; reg < 4; reg++) {
        float v = fmaxf(acc[mf][nt][reg] + bias[nt], 0.f);
        sw[(quad * 4 + reg) * 136 + nt * 16 + l16] = f2bf(v);
      }
    __syncthreads();
#pragma unroll
    for (int it = 0; it < 16; it++) {
      unsigned int v = *(const unsigned int*)(sw + it * 136 + lane * 2);
      int px = bx * 192 + wave * 48 + mf * 16 + it;
      int oh = px / 24, ow = px % 24;
      *(unsigned int*)(obase + ((oh + 1) * 26 + ow + 1) * 128 + lane * 2) = v;
    }
    __syncthreads();
  }
}

// ============ deconv3 (MFMA, role-swapped): act2p -> relu -> act3p [50][50][64] ============
__global__ __launch_bounds__(256, 2) void deconv3_kernel(
    const unsigned short* __restrict__ act2p, const unsigned short* __restrict__ w3b,
    const float* __restrict__ b3, unsigned short* __restrict__ act3p) {
  __shared__ unsigned short Blds[2][128 * 40];
  int tid = threadIdx.x;
  int bx = blockIdx.x, r = blockIdx.y, bt = blockIdx.z;
  int wave = tid >> 6, lane = tid & 63, quad = lane >> 4, l16 = lane & 15;
  const unsigned short* a2 = act2p + (size_t)bt * 86528u;
  unsigned short* a3 = act3p + (size_t)bt * 160000u;

  if (bx == 0 && r == 0) {
    uint4* hz = (uint4*)a3;
    uint4 z = {0, 0, 0, 0};
    for (int c = tid; c < 1568; c += 256) {
      int cell = c >> 3, v = c & 7;
      int row, col;
      if (cell < 50) { row = 0; col = cell; }
      else if (cell < 100) { row = 49; col = cell - 50; }
      else if (cell < 148) { row = cell - 99; col = 0; }
      else { row = cell - 147; col = 49; }
      hz[(row * 50 + col) * 8 + v] = z;
    }
  }

  const unsigned short* abase[3];
#pragma unroll
  for (int mf = 0; mf < 3; mf++) {
    int px = bx * 192 + wave * 48 + mf * 16 + l16;
    int i = px / 24, j = px % 24;
    abase[mf] = a2 + ((i + r) * 26 + j) * 128 + quad * 8;
  }
  int sn = tid >> 1, spart = tid & 1;
  const unsigned short* bptr = w3b + r * 98304 + sn * 768 + spart * 16;
  unsigned short* sdst = &Blds[0][0] + sn * 40 + spart * 16;

  floatx4 acc[3][8];
#pragma unroll
  for (int mf = 0; mf < 3; mf++)
#pragma unroll
    for (int nt = 0; nt < 8; nt++) acc[mf][nt] = (floatx4){0.f, 0.f, 0.f, 0.f};

  {
    uint4 s0 = *(const uint4*)(bptr);
    uint4 s1 = *(const uint4*)(bptr + 8);
    *(uint4*)(sdst) = s0;
    *(uint4*)(sdst + 8) = s1;
  }
  UV a_cur[3], a_nxt[3];
#pragma unroll
  for (int mf = 0; mf < 3; mf++) a_cur[mf].u = *(const uint4*)(abase[mf]);
  __syncthreads();

#pragma unroll 2
  for (int kk = 0; kk < 24; kk++) {
    int cur = kk & 1;
    UV bf[8];
#pragma unroll
    for (int nt = 0; nt < 8; nt++)
      bf[nt].u = *(const uint4*)(&Blds[cur][(nt * 16 + l16) * 40 + quad * 8]);
    uint4 ns0, ns1;
    if (kk < 23) {
      int kn = (kk + 1) * 32;
      ns0 = *(const uint4*)(bptr + kn);
      ns1 = *(const uint4*)(bptr + kn + 8);
      int tap = (kk + 1) >> 2, ic0 = ((kk + 1) & 3) * 32;
      int dh = tap / 3, dw = tap - dh * 3;
      int aoff = (dh * 26 + dw) * 128 + ic0;
#pragma unroll
      for (int mf = 0; mf < 3; mf++) a_nxt[mf].u = *(const uint4*)(abase[mf] + aoff);
    }
#pragma unroll
    for (int mf = 0; mf < 3; mf++)
#pragma unroll
      for (int nt = 0; nt < 8; nt++)
        acc[mf][nt] = __builtin_amdgcn_mfma_f32_16x16x32_bf16(a_cur[mf].s, bf[nt].s, acc[mf][nt], 0, 0, 0);
    if (kk < 23) {
      unsigned short* d = sdst + (1 - cur) * 5120;
      *(uint4*)(d) = ns0;
      *(uint4*)(d + 8) = ns1;
    }
    __syncthreads();
#pragma unroll
    for (int mf = 0; mf < 3; mf++) a_cur[mf] = a_nxt[mf];
  }

  float bias[8];
#pragma unroll
  for (int nt = 0; nt < 8; nt++) bias[nt] = b3[(nt * 16 + l16) & 63];
  unsigned short* sw = &Blds[0][0] + wave * 2176;
#pragma unroll
  for (int mf = 0; mf < 3; mf++) {
#pragma unroll
    for (int nt = 0; nt < 8; nt++)
#pragma unroll
      for (int reg = 0; reg < 4; reg++) {
        float v = fmaxf(acc[mf][nt][reg] + bias[nt], 0.f);
        sw[(quad * 4 + reg) * 136 + nt * 16 + l16] = f2bf(v);
      }
    __syncthreads();
#pragma unroll
    for (int it = 0; it < 16; it++) {
      unsigned int v = *(const unsigned int*)(sw + it * 136 + lane * 2);
      int px = bx * 192 + wave * 48 + mf * 16 + it;
      int i = px / 24, j = px % 24;
      *(unsigned int*)(a3 + ((2 * i + r + 1) * 50 + 2 * j + 1) * 64 + lane * 2) = v;
    }
    __syncthreads();
  }
}

// ============ deconv4 (MFMA, LDS-free, batched loads) + tanh: act3p -> out fp32 ============
// All 18 A-frags preloaded into regs (18 loads in flight, AITER-style vmcnt(N) drain);
// B (w4c, L1-hot) double-buffered one K-step ahead.
__global__ __launch_bounds__(256) void deconv4_kernel(
    const unsigned short* __restrict__ act3p, const unsigned short* __restrict__ w4c,
    const float* __restrict__ b4, float* __restrict__ out) {
  int tid = threadIdx.x;
  int wave = tid >> 6, lane = tid & 63, quad = lane >> 4, l16 = lane & 15;
  int bt = blockIdx.y;
  int tile = blockIdx.x * 4 + wave;
  int i = tile / 3, j0 = (tile - i * 3) * 16;
  const unsigned short* abase =
      act3p + (size_t)bt * 160000u + (size_t)((i * 50) + (j0 + l16)) * 64;
  const unsigned short* bbase = w4c + l16 * 576 + quad * 8;

  UV a[18];
#pragma unroll
  for (int kk = 0; kk < 18; kk++) {
    int t = kk >> 1;
    int dh = t / 3, dw = t - dh * 3;
    int icq = (kk & 1) * 32 + quad * 8;
    a[kk].u = *(const uint4*)(abase + (dh * 50 + dw) * 64 + icq);
  }

  UV bcur, bnxt;
  bcur.u = *(const uint4*)(bbase);
  floatx4 acc = (floatx4){0.f, 0.f, 0.f, 0.f};
#pragma unroll
  for (int kk = 0; kk < 18; kk++) {
    if (kk < 17) bnxt.u = *(const uint4*)(bbase + (kk + 1) * 32);
    acc = __builtin_amdgcn_mfma_f32_16x16x32_bf16(a[kk].s, bcur.s, acc, 0, 0, 0);
    bcur = bnxt;
  }

  int n = l16;
  if (n < 12) {
    int cls = n / 3, oc = n - cls * 3;
    int r = cls >> 1, s = cls & 1;
    float bias = b4[oc];
    int oh = 2 * i + r;
    float* obase = out + (size_t)bt * 27648u + oc * 9216 + oh * 96 + s;
#pragma unroll
    for (int reg = 0; reg < 4; reg++) {
      int jj = j0 + quad * 4 + reg;
      obase[2 * jj] = ftanh(acc[reg] + bias);
    }
  }
}

extern "C" void kernel_launch(void* const* d_in, const int* in_sizes, int n_in,
                              void* d_out, int out_size, void* d_ws, size_t ws_size,
                              hipStream_t stream) {
  const float* ident = (const float*)d_in[0];
  const float* lm = (const float*)d_in[1];
  const float* w1 = (const float*)d_in[2];
  const float* b1 = (const float*)d_in[3];
  const float* w2 = (const float*)d_in[4];
  const float* b2 = (const float*)d_in[5];
  const float* w3 = (const float*)d_in[6];
  const float* b3 = (const float*)d_in[7];
  const float* w4 = (const float*)d_in[8];
  const float* b4 = (const float*)d_in[9];
  float* out = (float*)d_out;
  char* ws = (char*)d_ws;
  unsigned short* identp = (unsigned short*)(ws + IDENTP_OFF);
  unsigned short* hmp = (unsigned short*)(ws + HMP_OFF);
  unsigned short* act1cl = (unsigned short*)(ws + ACT1CL_OFF);
  unsigned short* act2p = (unsigned short*)(ws + ACT2P_OFF);
  unsigned short* act3p = (unsigned short*)(ws + ACT3P_OFF);
  unsigned short* w2b = (unsigned short*)(ws + W2B_OFF);
  unsigned short* w3b = (unsigned short*)(ws + W3B_OFF);
  unsigned short* w1b = (unsigned short*)(ws + W1B_OFF);
  unsigned short* w4c = (unsigned short*)(ws + W4C_OFF);

  prep_kernel<<<dim3(954), 256, 0, stream>>>(lm, ident, w1, w2, w3, w4, identp, hmp,
                                             w1b, w2b, w3b, w4c, act1cl, act2p);
  conv1_kernel<<<dim3(36, 256), 256, 0, stream>>>(identp, hmp, w1b, b1, act1cl);
  conv2_kernel<<<dim3(3, 256), 256, 0, stream>>>(act1cl, w2b, b2, act2p);
  deconv3_kernel<<<dim3(3, 2, 256), 256, 0, stream>>>(act2p, w3b, b3, act3p);
  deconv4_kernel<<<dim3(36, 256), 256, 0, stream>>>(act3p, w4c, b4, out);
}

// Round 8
// 438.821 us; speedup vs baseline: 1.1618x; 1.0041x over previous
//
#include <hip/hip_runtime.h>

// ---- workspace layout (bytes) ----
#define IDENTP_OFF 0u            // identp: 8*3*98*100*2 = 470400
#define HMP_OFF    470400u       // hmp: 256*98*100*2 = 5017600
#define ACT1CL_OFF 5488000u      // act1cl: 256*50*52*64*2 = 85196800 (ends 90684800)
#define ACT3P_OFF  470400u       // act3p: 256*50*50*64*2 = 81920000 — aliases hmp+act1cl (dead after conv2)
#define ACT2P_OFF  90684800u     // act2p: 256*26*26*128*2 = 44302336
#define W2B_OFF    134987136u    // w2b: 128*1024*2 = 262144
#define W3B_OFF    135249280u    // w3b: 2*128*768*2 = 393216
#define W1B_OFF    135642496u    // w1b: 64*64*2 = 8192
#define W4C_OFF    135650688u    // w4c: 16*576*2 = 18432

using short8  = __attribute__((ext_vector_type(8))) short;
using floatx4 = __attribute__((ext_vector_type(4))) float;
union UV { uint4 u; short8 s; };

static __device__ __forceinline__ float bf2f(unsigned short u) {
  union { unsigned int i; float f; } v; v.i = ((unsigned int)u) << 16; return v.f;
}
static __device__ __forceinline__ unsigned short f2bf(float f) {
  union { float f; unsigned int i; } v; v.f = f;
  unsigned int x = v.i;
  return (unsigned short)((x + 0x7FFFu + ((x >> 16) & 1u)) >> 16);  // RNE
}
static __device__ __forceinline__ uint4 pack8(const unsigned short* v) {
  uint4 p;
  p.x = (unsigned)v[0] | ((unsigned)v[1] << 16);
  p.y = (unsigned)v[2] | ((unsigned)v[3] << 16);
  p.z = (unsigned)v[4] | ((unsigned)v[5] << 16);
  p.w = (unsigned)v[6] | ((unsigned)v[7] << 16);
  return p;
}
static __device__ __forceinline__ float ftanh(float x) {
  x = fminf(fmaxf(x, -10.f), 10.f);
  float e = __expf(2.f * x);
  return (e - 1.f) * __builtin_amdgcn_rcpf(e + 1.f);
}

// ============ prep ============
__global__ __launch_bounds__(256) void prep_kernel(
    const float* __restrict__ lm, const float* __restrict__ ident,
    const float* __restrict__ w1, const float* __restrict__ w2,
    const float* __restrict__ w3, const float* __restrict__ w4,
    unsigned short* __restrict__ identp, unsigned short* __restrict__ hmp,
    unsigned short* __restrict__ w1b, unsigned short* __restrict__ w2b,
    unsigned short* __restrict__ w3b, unsigned short* __restrict__ w4c,
    unsigned short* __restrict__ act1cl, unsigned short* __restrict__ act2p) {
  int bid = blockIdx.x, tid = threadIdx.x;
  if (bid < 256) {
    // hmp [bt][98][100]
    unsigned int* h32 = (unsigned int*)(hmp + bid * 9800);
    for (int i = tid; i < 4900; i += 256) h32[i] = 0u;
    __syncthreads();
    if (tid < 68) {
      float x = lm[bid * 136 + tid * 2 + 0] * 95.0f;
      float y = lm[bid * 136 + tid * 2 + 1] * 95.0f;
      int ix = (int)x, iy = (int)y;
      if (ix >= 0 && ix < 96 && iy >= 0 && iy < 96)
        hmp[bid * 9800 + (iy + 1) * 100 + (ix + 1)] = 0x3F80;
    }
  } else if (bid < 320) {
    // w2b [oc128][k'1024], k' = (kh*4+kw)*64 + ic ; w2 native k = ic*16+kh*4+kw
    int e = (bid - 256) * 2048 + tid * 8;
    int oc = e >> 10, kp = e & 1023;
    int tap = kp >> 6, ic0 = kp & 63;
    unsigned short v[8];
#pragma unroll
    for (int j = 0; j < 8; j++) v[j] = f2bf(w2[oc * 1024 + (ic0 + j) * 16 + tap]);
    *(uint4*)(w2b + e) = pack8(v);
  } else if (bid < 416) {
    // w3b [r2][n128][k768]: n=s*64+oc, k=(dh*3+dw)*128+ic; a=1-dh, b=s+1-dw
    int idx = (bid - 320) * 2048 + tid * 8;
    int r = idx / 98304;
    int rem = idx - r * 98304;
    int n = rem / 768, k = rem - n * 768;
    int s = n >> 6, oc = n & 63;
    int tap = k >> 7, ic0 = k & 127;
    int dh = tap / 3, dw = tap - dh * 3;
    int a = 1 - dh, bb = s + 1 - dw;
    unsigned short v[8];
    if (bb >= 0 && bb <= 1) {
      int kh = 2 * a + 1 - r, kw = 2 * bb + 1 - s;
#pragma unroll
      for (int j = 0; j < 8; j++)
        v[j] = f2bf(w3[((ic0 + j) * 64 + oc) * 16 + kh * 4 + kw]);
    } else {
#pragma unroll
      for (int j = 0; j < 8; j++) v[j] = 0;
    }
    *(uint4*)(w3b + idx) = pack8(v);
  } else if (bid < 440) {
    // identp [b*3+ic][98][100]
    int bci = bid - 416;
    const float* src = ident + bci * 9216;
    unsigned short* dst = identp + bci * 9800;
    for (int i = tid; i < 9800; i += 256) {
      int row = i / 100, col = i - row * 100;
      bool in = (row >= 1) && (row <= 96) && (col >= 1) && (col <= 96);
      dst[i] = in ? f2bf(src[(row - 1) * 96 + (col - 1)]) : (unsigned short)0;
    }
  } else if (bid < 696) {
    // act1cl halo zero [50][52][64]
    unsigned short* base = act1cl + (size_t)(bid - 440) * 166400u;
    for (int c = tid; c < 1568; c += 256) {
      int cell = c >> 3, v = c & 7;
      int row, col;
      if (cell < 50) { row = 0; col = cell; }
      else if (cell < 100) { row = 49; col = cell - 50; }
      else if (cell < 148) { row = cell - 99; col = 0; }
      else { row = cell - 147; col = 49; }
      *(uint4*)(base + (row * 52 + col) * 64 + v * 8) = (uint4){0, 0, 0, 0};
    }
  } else if (bid < 952) {
    // act2p halo zero [26][26][128]
    uint4* b4p = (uint4*)(act2p + (size_t)(bid - 696) * 86528u);
    uint4 z = {0, 0, 0, 0};
    for (int c = tid; c < 1600; c += 256) {
      int cell = c >> 4, v = c & 15;
      int row, col;
      if (cell < 26) { row = 0; col = cell; }
      else if (cell < 52) { row = 25; col = cell - 26; }
      else if (cell < 76) { row = cell - 51; col = 0; }
      else { row = cell - 75; col = 25; }
      b4p[(row * 26 + col) * 16 + v] = z;
    }
  } else if (bid == 952) {
    // w1b [64 oc][64 k native]
    int e = tid * 16;
    unsigned short v[16];
#pragma unroll
    for (int q = 0; q < 4; q++) {
      float4 f = *(const float4*)(w1 + e + q * 4);
      v[q * 4 + 0] = f2bf(f.x); v[q * 4 + 1] = f2bf(f.y);
      v[q * 4 + 2] = f2bf(f.z); v[q * 4 + 3] = f2bf(f.w);
    }
    *(uint4*)(w1b + e) = pack8(v);
    *(uint4*)(w1b + e + 8) = pack8(v + 8);
  } else {
    // w4c [n16][k576]: k=(dh*3+dw)*64+ic; n=cls*3+oc
    for (int idx = tid; idx < 9216; idx += 256) {
      int n = idx / 576, k = idx - n * 576;
      int t = k >> 6, ic = k & 63;
      int dh = t / 3, dw = t - dh * 3;
      unsigned short val = 0;
      if (n < 12) {
        int cls = n / 3, oc = n - cls * 3;
        int r = cls >> 1, s = cls & 1;
        int a = r - dh + 1, b = s - dw + 1;
        if (a >= 0 && a < 2 && b >= 0 && b < 2) {
          int kh = 2 * a + 1 - r, kw = 2 * b + 1 - s;
          val = f2bf(w4[ic * 48 + oc * 16 + kh * 4 + kw]);
        }
      }
      w4c[idx] = val;
    }
  }
}

// ============ conv1 (MFMA, role-swapped): -> act1cl [50][52][64] ============
__global__ __launch_bounds__(256) void conv1_kernel(
    const unsigned short* __restrict__ identp, const unsigned short* __restrict__ hmp,
    const unsigned short* __restrict__ w1b, const float* __restrict__ b1,
    unsigned short* __restrict__ act1cl) {
  __shared__ unsigned short stage[4608];  // 4 waves x 16 px x 72
  int tid = threadIdx.x;
  int bx = blockIdx.x, bt = blockIdx.y;
  int b = bt >> 5;
  int wave = tid >> 6, lane = tid & 63, quad = lane >> 4, l16 = lane & 15;
  int px0 = bx * 64 + wave * 16;
  int pxa = px0 + l16;
  int oh = pxa / 48, ow = pxa % 48;

  floatx4 acc[4];
#pragma unroll
  for (int nt = 0; nt < 4; nt++) acc[nt] = (floatx4){0.f, 0.f, 0.f, 0.f};

#pragma unroll
  for (int kk = 0; kk < 2; kk++) {
    int k0 = kk * 32 + quad * 8;
    int ic = k0 >> 4, khp = (k0 >> 3) & 1;
    const unsigned short* src = (ic < 3) ? identp + (b * 3 + ic) * 9800
                                         : hmp + bt * 9800;
    const unsigned short* p = src + (2 * oh + khp * 2) * 100 + 2 * ow;
    UV a;
    a.u.x = *(const unsigned int*)(p);
    a.u.y = *(const unsigned int*)(p + 2);
    a.u.z = *(const unsigned int*)(p + 100);
    a.u.w = *(const unsigned int*)(p + 102);
#pragma unroll
    for (int nt = 0; nt < 4; nt++) {
      UV bv;
      bv.u = *(const uint4*)(w1b + (nt * 16 + l16) * 64 + kk * 32 + quad * 8);
      acc[nt] = __builtin_amdgcn_mfma_f32_16x16x32_bf16(a.s, bv.s, acc[nt], 0, 0, 0);
    }
  }

  float bias[4];
#pragma unroll
  for (int nt = 0; nt < 4; nt++) bias[nt] = b1[nt * 16 + l16];
  unsigned short* sw = stage + wave * 1152;
#pragma unroll
  for (int nt = 0; nt < 4; nt++)
#pragma unroll
    for (int reg = 0; reg < 4; reg++) {
      float v = fmaxf(acc[nt][reg] + bias[nt], 0.f);
      sw[(quad * 4 + reg) * 72 + nt * 16 + l16] = f2bf(v);
    }
  __syncthreads();
  int oh0 = px0 / 48, ow0 = px0 % 48;
  unsigned short* gout = act1cl + (size_t)bt * 166400u + ((oh0 + 1) * 52 + ow0 + 1) * 64;
#pragma unroll
  for (int it = 0; it < 8; it++) {
    int pl = it * 2 + (lane >> 5);
    unsigned int v = *(const unsigned int*)(sw + pl * 72 + (lane & 31) * 2);
    *(unsigned int*)(gout + pl * 64 + (lane & 31) * 2) = v;
  }
}

// ============ conv2 (MFMA, role-swapped): act1cl -> relu -> act2p [26][26][128] ============
__global__ __launch_bounds__(256, 2) void conv2_kernel(
    const unsigned short* __restrict__ act1cl, const unsigned short* __restrict__ w2b,
    const float* __restrict__ b2, unsigned short* __restrict__ act2p) {
  __shared__ unsigned short Blds[2][128 * 40];  // 20480 B
  int tid = threadIdx.x;
  int bx = blockIdx.x, bt = blockIdx.y;
  int wave = tid >> 6, lane = tid & 63, quad = lane >> 4, l16 = lane & 15;
  const unsigned short* frame = act1cl + (size_t)bt * 166400u;
  const unsigned short* abase[3];
#pragma unroll
  for (int mf = 0; mf < 3; mf++) {
    int px = bx * 192 + wave * 48 + mf * 16 + l16;
    int oh = px / 24, ow = px % 24;
    abase[mf] = frame + ((2 * oh) * 52 + 2 * ow) * 64 + quad * 8;
  }
  int sn = tid >> 1, spart = tid & 1;
  const unsigned short* bptr = w2b + sn * 1024 + spart * 16;
  unsigned short* sdst = &Blds[0][0] + sn * 40 + spart * 16;

  floatx4 acc[3][8];
#pragma unroll
  for (int mf = 0; mf < 3; mf++)
#pragma unroll
    for (int nt = 0; nt < 8; nt++) acc[mf][nt] = (floatx4){0.f, 0.f, 0.f, 0.f};

  {
    uint4 s0 = *(const uint4*)(bptr);
    uint4 s1 = *(const uint4*)(bptr + 8);
    *(uint4*)(sdst) = s0;
    *(uint4*)(sdst + 8) = s1;
  }
  UV a_cur[3], a_nxt[3];
#pragma unroll
  for (int mf = 0; mf < 3; mf++) a_cur[mf].u = *(const uint4*)(abase[mf]);
  __syncthreads();

#pragma unroll 2
  for (int kk = 0; kk < 32; kk++) {
    int cur = kk & 1;
    UV bf[8];
#pragma unroll
    for (int nt = 0; nt < 8; nt++)
      bf[nt].u = *(const uint4*)(&Blds[cur][(nt * 16 + l16) * 40 + quad * 8]);
    uint4 ns0, ns1;
    if (kk < 31) {
      int kn = (kk + 1) * 32;
      ns0 = *(const uint4*)(bptr + kn);
      ns1 = *(const uint4*)(bptr + kn + 8);
      int tap = (kk + 1) >> 1, ic0 = ((kk + 1) & 1) * 32;
      int kh = tap >> 2, kw = tap & 3;
      int aoff = (kh * 52 + kw) * 64 + ic0;
#pragma unroll
      for (int mf = 0; mf < 3; mf++) a_nxt[mf].u = *(const uint4*)(abase[mf] + aoff);
    }
#pragma unroll
    for (int mf = 0; mf < 3; mf++)
#pragma unroll
      for (int nt = 0; nt < 8; nt++)
        acc[mf][nt] = __builtin_amdgcn_mfma_f32_16x16x32_bf16(a_cur[mf].s, bf[nt].s, acc[mf][nt], 0, 0, 0);
    if (kk < 31) {
      unsigned short* d = sdst + (1 - cur) * 5120;
      *(uint4*)(d) = ns0;
      *(uint4*)(d + 8) = ns1;
    }
    __syncthreads();
#pragma unroll
    for (int mf = 0; mf < 3; mf++) a_cur[mf] = a_nxt[mf];
  }

  float bias[8];
#pragma unroll
  for (int nt = 0; nt < 8; nt++) bias[nt] = b2[nt * 16 + l16];
  unsigned short* sw = &Blds[0][0] + wave * 2176;  // 16 px x 136
  unsigned short* obase = act2p + (size_t)bt * 86528u;
#pragma unroll
  for (int mf = 0; mf < 3; mf++) {
#pragma unroll
    for (int nt = 0; nt < 8; nt++)
#pragma unroll
      for (int reg = 0; reg < 4; reg++) {
        float v = fmaxf(acc[mf][nt][reg] + bias[nt], 0.f);
        sw[(quad * 4 + reg) * 136 + nt * 16 + l16] = f2bf(v);
      }
    __syncthreads();
#pragma unroll
    for (int it = 0; it < 16; it++) {
      unsigned int v = *(const unsigned int*)(sw + it * 136 + lane * 2);
      int px = bx * 192 + wave * 48 + mf * 16 + it;
      int oh = px / 24, ow = px % 24;
      *(unsigned int*)(obase + ((oh + 1) * 26 + ow + 1) * 128 + lane * 2) = v;
    }
    __syncthreads();
  }
}

// ============ deconv3 (MFMA, role-swapped): act2p -> relu -> act3p [50][50][64] ============
__global__ __launch_bounds__(256, 2) void deconv3_kernel(
    const unsigned short* __restrict__ act2p, const unsigned short* __restrict__ w3b,
    const float* __restrict__ b3, unsigned short* __restrict__ act3p) {
  __shared__ unsigned short Blds[2][128 * 40];
  int tid = threadIdx.x;
  int bx = blockIdx.x, r = blockIdx.y, bt = blockIdx.z;
  int wave = tid >> 6, lane = tid & 63, quad = lane >> 4, l16 = lane & 15;
  const unsigned short* a2 = act2p + (size_t)bt * 86528u;
  unsigned short* a3 = act3p + (size_t)bt * 160000u;

  if (bx == 0 && r == 0) {
    uint4* hz = (uint4*)a3;
    uint4 z = {0, 0, 0, 0};
    for (int c = tid; c < 1568; c += 256) {
      int cell = c >> 3, v = c & 7;
      int row, col;
      if (cell < 50) { row = 0; col = cell; }
      else if (cell < 100) { row = 49; col = cell - 50; }
      else if (cell < 148) { row = cell - 99; col = 0; }
      else { row = cell - 147; col = 49; }
      hz[(row * 50 + col) * 8 + v] = z;
    }
  }

  const unsigned short* abase[3];
#pragma unroll
  for (int mf = 0; mf < 3; mf++) {
    int px = bx * 192 + wave * 48 + mf * 16 + l16;
    int i = px / 24, j = px % 24;
    abase[mf] = a2 + ((i + r) * 26 + j) * 128 + quad * 8;
  }
  int sn = tid >> 1, spart = tid & 1;
  const unsigned short* bptr = w3b + r * 98304 + sn * 768 + spart * 16;
  unsigned short* sdst = &Blds[0][0] + sn * 40 + spart * 16;

  floatx4 acc[3][8];
#pragma unroll
  for (int mf = 0; mf < 3; mf++)
#pragma unroll
    for (int nt = 0; nt < 8; nt++) acc[mf][nt] = (floatx4){0.f, 0.f, 0.f, 0.f};

  {
    uint4 s0 = *(const uint4*)(bptr);
    uint4 s1 = *(const uint4*)(bptr + 8);
    *(uint4*)(sdst) = s0;
    *(uint4*)(sdst + 8) = s1;
  }
  UV a_cur[3], a_nxt[3];
#pragma unroll
  for (int mf = 0; mf < 3; mf++) a_cur[mf].u = *(const uint4*)(abase[mf]);
  __syncthreads();

#pragma unroll 2
  for (int kk = 0; kk < 24; kk++) {
    int cur = kk & 1;
    UV bf[8];
#pragma unroll
    for (int nt = 0; nt < 8; nt++)
      bf[nt].u = *(const uint4*)(&Blds[cur][(nt * 16 + l16) * 40 + quad * 8]);
    uint4 ns0, ns1;
    if (kk < 23) {
      int kn = (kk + 1) * 32;
      ns0 = *(const uint4*)(bptr + kn);
      ns1 = *(const uint4*)(bptr + kn + 8);
      int tap = (kk + 1) >> 2, ic0 = ((kk + 1) & 3) * 32;
      int dh = tap / 3, dw = tap - dh * 3;
      int aoff = (dh * 26 + dw) * 128 + ic0;
#pragma unroll
      for (int mf = 0; mf < 3; mf++) a_nxt[mf].u = *(const uint4*)(abase[mf] + aoff);
    }
#pragma unroll
    for (int mf = 0; mf < 3; mf++)
#pragma unroll
      for (int nt = 0; nt < 8; nt++)
        acc[mf][nt] = __builtin_amdgcn_mfma_f32_16x16x32_bf16(a_cur[mf].s, bf[nt].s, acc[mf][nt], 0, 0, 0);
    if (kk < 23) {
      unsigned short* d = sdst + (1 - cur) * 5120;
      *(uint4*)(d) = ns0;
      *(uint4*)(d + 8) = ns1;
    }
    __syncthreads();
#pragma unroll
    for (int mf = 0; mf < 3; mf++) a_cur[mf] = a_nxt[mf];
  }

  float bias[8];
#pragma unroll
  for (int nt = 0; nt < 8; nt++) bias[nt] = b3[(nt * 16 + l16) & 63];
  unsigned short* sw = &Blds[0][0] + wave * 2176;
#pragma unroll
  for (int mf = 0; mf < 3; mf++) {
#pragma unroll
    for (int nt = 0; nt < 8; nt++)
#pragma unroll
      for (int reg = 0; reg < 4; reg++) {
        float v = fmaxf(acc[mf][nt][reg] + bias[nt], 0.f);
        sw[(quad * 4 + reg) * 136 + nt * 16 + l16] = f2bf(v);
      }
    __syncthreads();
#pragma unroll
    for (int it = 0; it < 16; it++) {
      unsigned int v = *(const unsigned int*)(sw + it * 136 + lane * 2);
      int px = bx * 192 + wave * 48 + mf * 16 + it;
      int i = px / 24, j = px % 24;
      *(unsigned int*)(a3 + ((2 * i + r + 1) * 50 + 2 * j + 1) * 64 + lane * 2) = v;
    }
    __syncthreads();
  }
}

// ============ deconv4 (MFMA, LDS-free, FORCED batched loads) + tanh ============
// 18 A-frags + 18 B-frags all issued before a sched_barrier(0): compiler cannot
// sink them to use sites -> 36 loads in flight per wave (AITER-style vmcnt drain).
__global__ __launch_bounds__(256) void deconv4_kernel(
    const unsigned short* __restrict__ act3p, const unsigned short* __restrict__ w4c,
    const float* __restrict__ b4, float* __restrict__ out) {
  int tid = threadIdx.x;
  int wave = tid >> 6, lane = tid & 63, quad = lane >> 4, l16 = lane & 15;
  int bt = blockIdx.y;
  int tile = blockIdx.x * 4 + wave;
  int i = tile / 3, j0 = (tile - i * 3) * 16;
  const unsigned short* abase =
      act3p + (size_t)bt * 160000u + (size_t)((i * 50) + (j0 + l16)) * 64;
  const unsigned short* bbase = w4c + l16 * 576 + quad * 8;

  UV a[18], b[18];
#pragma unroll
  for (int kk = 0; kk < 18; kk++) {
    int t = kk >> 1;
    int dh = t / 3, dw = t - dh * 3;
    int icq = (kk & 1) * 32 + quad * 8;
    a[kk].u = *(const uint4*)(abase + (dh * 50 + dw) * 64 + icq);
    b[kk].u = *(const uint4*)(bbase + kk * 32);
  }
  __builtin_amdgcn_sched_barrier(0);  // pin: all 36 loads issue before any MFMA

  floatx4 acc = (floatx4){0.f, 0.f, 0.f, 0.f};
#pragma unroll
  for (int kk = 0; kk < 18; kk++)
    acc = __builtin_amdgcn_mfma_f32_16x16x32_bf16(a[kk].s, b[kk].s, acc, 0, 0, 0);

  int n = l16;
  if (n < 12) {
    int cls = n / 3, oc = n - cls * 3;
    int r = cls >> 1, s = cls & 1;
    float bias = b4[oc];
    int oh = 2 * i + r;
    float* obase = out + (size_t)bt * 27648u + oc * 9216 + oh * 96 + s;
#pragma unroll
    for (int reg = 0; reg < 4; reg++) {
      int jj = j0 + quad * 4 + reg;
      obase[2 * jj] = ftanh(acc[reg] + bias);
    }
  }
}

extern "C" void kernel_launch(void* const* d_in, const int* in_sizes, int n_in,
                              void* d_out, int out_size, void* d_ws, size_t ws_size,
                              hipStream_t stream) {
  const float* ident = (const float*)d_in[0];
  const float* lm = (const float*)d_in[1];
  const float* w1 = (const float*)d_in[2];
  const float* b1 = (const float*)d_in[3];
  const float* w2 = (const float*)d_in[4];
  const float* b2 = (const float*)d_in[5];
  const float* w3 = (const float*)d_in[6];
  const float* b3 = (const float*)d_in[7];
  const float* w4 = (const float*)d_in[8];
  const float* b4 = (const float*)d_in[9];
  float* out = (float*)d_out;
  char* ws = (char*)d_ws;
  unsigned short* identp = (unsigned short*)(ws + IDENTP_OFF);
  unsigned short* hmp = (unsigned short*)(ws + HMP_OFF);
  unsigned short* act1cl = (unsigned short*)(ws + ACT1CL_OFF);
  unsigned short* act2p = (unsigned short*)(ws + ACT2P_OFF);
  unsigned short* act3p = (unsigned short*)(ws + ACT3P_OFF);
  unsigned short* w2b = (unsigned short*)(ws + W2B_OFF);
  unsigned short* w3b = (unsigned short*)(ws + W3B_OFF);
  unsigned short* w1b = (unsigned short*)(ws + W1B_OFF);
  unsigned short* w4c = (unsigned short*)(ws + W4C_OFF);

  prep_kernel<<<dim3(954), 256, 0, stream>>>(lm, ident, w1, w2, w3, w4, identp, hmp,
                                             w1b, w2b, w3b, w4c, act1cl, act2p);
  conv1_kernel<<<dim3(36, 256), 256, 0, stream>>>(identp, hmp, w1b, b1, act1cl);
  conv2_kernel<<<dim3(3, 256), 256, 0, stream>>>(act1cl, w2b, b2, act2p);
  deconv3_kernel<<<dim3(3, 2, 256), 256, 0, stream>>>(act2p, w3b, b3, act3p);
  deconv4_kernel<<<dim3(36, 256), 256, 0, stream>>>(act3p, w4c, b4, out);
}

// Round 9
// 320.018 us; speedup vs baseline: 1.5931x; 1.3712x over previous
//
#include <hip/hip_runtime.h>

// ---- workspace layout (bytes) ----
#define IDENTP_OFF 0u            // identp: 8*3*98*100*2 = 470400
#define HMP_OFF    470400u       // hmp: 256*98*100*2 = 5017600
#define ACT1CL_OFF 5488000u      // act1cl: 256*50*52*64*2 = 85196800 (ends 90684800)
#define ACT3P_OFF  470400u       // act3p: 256*50*50*64*2 = 81920000 — aliases hmp+act1cl (dead after conv2)
#define ACT2P_OFF  90684800u     // act2p: 256*26*26*128*2 = 44302336
#define W2B_OFF    134987136u    // w2t: [32 kk][128n*32el] = 262144
#define W3B_OFF    135249280u    // w3t: [2 r][24 kk][128n*32el] = 393216
#define W1B_OFF    135642496u    // w1b: 64*64*2 = 8192
#define W4C_OFF    135650688u    // w4c: 16*576*2 = 18432

using short8  = __attribute__((ext_vector_type(8))) short;
using floatx4 = __attribute__((ext_vector_type(4))) float;
union UV { uint4 u; short8 s; };

static __device__ __forceinline__ float bf2f(unsigned short u) {
  union { unsigned int i; float f; } v; v.i = ((unsigned int)u) << 16; return v.f;
}
static __device__ __forceinline__ unsigned short f2bf(float f) {
  union { float f; unsigned int i; } v; v.f = f;
  unsigned int x = v.i;
  return (unsigned short)((x + 0x7FFFu + ((x >> 16) & 1u)) >> 16);  // RNE
}
static __device__ __forceinline__ uint4 pack8(const unsigned short* v) {
  uint4 p;
  p.x = (unsigned)v[0] | ((unsigned)v[1] << 16);
  p.y = (unsigned)v[2] | ((unsigned)v[3] << 16);
  p.z = (unsigned)v[4] | ((unsigned)v[5] << 16);
  p.w = (unsigned)v[6] | ((unsigned)v[7] << 16);
  return p;
}
static __device__ __forceinline__ float ftanh(float x) {
  x = fminf(fmaxf(x, -10.f), 10.f);
  float e = __expf(2.f * x);
  return (e - 1.f) * __builtin_amdgcn_rcpf(e + 1.f);
}

// ============ prep ============
__global__ __launch_bounds__(256) void prep_kernel(
    const float* __restrict__ lm, const float* __restrict__ ident,
    const float* __restrict__ w1, const float* __restrict__ w2,
    const float* __restrict__ w3, const float* __restrict__ w4,
    unsigned short* __restrict__ identp, unsigned short* __restrict__ hmp,
    unsigned short* __restrict__ w1b, unsigned short* __restrict__ w2t,
    unsigned short* __restrict__ w3t, unsigned short* __restrict__ w4c,
    unsigned short* __restrict__ act1cl, unsigned short* __restrict__ act2p) {
  int bid = blockIdx.x, tid = threadIdx.x;
  if (bid < 256) {
    // hmp [bt][98][100]
    unsigned int* h32 = (unsigned int*)(hmp + bid * 9800);
    for (int i = tid; i < 4900; i += 256) h32[i] = 0u;
    __syncthreads();
    if (tid < 68) {
      float x = lm[bid * 136 + tid * 2 + 0] * 95.0f;
      float y = lm[bid * 136 + tid * 2 + 1] * 95.0f;
      int ix = (int)x, iy = (int)y;
      if (ix >= 0 && ix < 96 && iy >= 0 && iy < 96)
        hmp[bid * 9800 + (iy + 1) * 100 + (ix + 1)] = 0x3F80;
    }
  } else if (bid < 320) {
    // w2t [kk32][n128*32el]: element (kk,n,e): k'=kk*32+e, k'=tap*64+ic
    int idx = (bid - 256) * 2048 + tid * 8;
    int kk = idx >> 12, rem = idx & 4095;
    int n = rem >> 5, e = rem & 31;
    unsigned short v[8];
#pragma unroll
    for (int j = 0; j < 8; j++) {
      int t = kk * 32 + e + j;
      int tap = t >> 6, ic = t & 63;
      v[j] = f2bf(w2[n * 1024 + ic * 16 + tap]);
    }
    *(uint4*)(w2t + idx) = pack8(v);
  } else if (bid < 416) {
    // w3t [r2][kk24][n128*32el]: n=s*64+oc, k=kk*32+e=(dh*3+dw)*128+ic
    int idx = (bid - 320) * 2048 + tid * 8;
    int r = idx / 98304;
    int rem2 = idx - r * 98304;
    int kk = rem2 >> 12, rem3 = rem2 & 4095;
    int n = rem3 >> 5, e = rem3 & 31;
    int s = n >> 6, oc = n & 63;
    unsigned short v[8];
#pragma unroll
    for (int j = 0; j < 8; j++) {
      int k = kk * 32 + e + j;
      int tap = k >> 7, ic = k & 127;
      int dh = tap / 3, dw = tap - dh * 3;
      int a = 1 - dh, bb = s + 1 - dw;
      unsigned short val = 0;
      if (bb >= 0 && bb <= 1) {
        int kh = 2 * a + 1 - r, kw = 2 * bb + 1 - s;
        val = f2bf(w3[ic * 1024 + oc * 16 + kh * 4 + kw]);
      }
      v[j] = val;
    }
    *(uint4*)(w3t + idx) = pack8(v);
  } else if (bid < 440) {
    // identp [b*3+ic][98][100]
    int bci = bid - 416;
    const float* src = ident + bci * 9216;
    unsigned short* dst = identp + bci * 9800;
    for (int i = tid; i < 9800; i += 256) {
      int row = i / 100, col = i - row * 100;
      bool in = (row >= 1) && (row <= 96) && (col >= 1) && (col <= 96);
      dst[i] = in ? f2bf(src[(row - 1) * 96 + (col - 1)]) : (unsigned short)0;
    }
  } else if (bid < 696) {
    // act1cl halo zero [50][52][64]
    unsigned short* base = act1cl + (size_t)(bid - 440) * 166400u;
    for (int c = tid; c < 1568; c += 256) {
      int cell = c >> 3, v = c & 7;
      int row, col;
      if (cell < 50) { row = 0; col = cell; }
      else if (cell < 100) { row = 49; col = cell - 50; }
      else if (cell < 148) { row = cell - 99; col = 0; }
      else { row = cell - 147; col = 49; }
      *(uint4*)(base + (row * 52 + col) * 64 + v * 8) = (uint4){0, 0, 0, 0};
    }
  } else if (bid < 952) {
    // act2p halo zero [26][26][128]
    uint4* b4p = (uint4*)(act2p + (size_t)(bid - 696) * 86528u);
    uint4 z = {0, 0, 0, 0};
    for (int c = tid; c < 1600; c += 256) {
      int cell = c >> 4, v = c & 15;
      int row, col;
      if (cell < 26) { row = 0; col = cell; }
      else if (cell < 52) { row = 25; col = cell - 26; }
      else if (cell < 76) { row = cell - 51; col = 0; }
      else { row = cell - 75; col = 25; }
      b4p[(row * 26 + col) * 16 + v] = z;
    }
  } else if (bid == 952) {
    // w1b [64 oc][64 k native]
    int e = tid * 16;
    unsigned short v[16];
#pragma unroll
    for (int q = 0; q < 4; q++) {
      float4 f = *(const float4*)(w1 + e + q * 4);
      v[q * 4 + 0] = f2bf(f.x); v[q * 4 + 1] = f2bf(f.y);
      v[q * 4 + 2] = f2bf(f.z); v[q * 4 + 3] = f2bf(f.w);
    }
    *(uint4*)(w1b + e) = pack8(v);
    *(uint4*)(w1b + e + 8) = pack8(v + 8);
  } else {
    // w4c [n16][k576]: k=(dh*3+dw)*64+ic; n=cls*3+oc
    for (int idx = tid; idx < 9216; idx += 256) {
      int n = idx / 576, k = idx - n * 576;
      int t = k >> 6, ic = k & 63;
      int dh = t / 3, dw = t - dh * 3;
      unsigned short val = 0;
      if (n < 12) {
        int cls = n / 3, oc = n - cls * 3;
        int r = cls >> 1, s = cls & 1;
        int a = r - dh + 1, b = s - dw + 1;
        if (a >= 0 && a < 2 && b >= 0 && b < 2) {
          int kh = 2 * a + 1 - r, kw = 2 * b + 1 - s;
          val = f2bf(w4[ic * 48 + oc * 16 + kh * 4 + kw]);
        }
      }
      w4c[idx] = val;
    }
  }
}

// ============ conv1 (MFMA, role-swapped): -> act1cl [50][52][64] ============
__global__ __launch_bounds__(256) void conv1_kernel(
    const unsigned short* __restrict__ identp, const unsigned short* __restrict__ hmp,
    const unsigned short* __restrict__ w1b, const float* __restrict__ b1,
    unsigned short* __restrict__ act1cl) {
  __shared__ unsigned short stage[4608];  // 4 waves x 16 px x 72
  int tid = threadIdx.x;
  int bx = blockIdx.x, bt = blockIdx.y;
  int b = bt >> 5;
  int wave = tid >> 6, lane = tid & 63, quad = lane >> 4, l16 = lane & 15;
  int px0 = bx * 64 + wave * 16;
  int pxa = px0 + l16;
  int oh = pxa / 48, ow = pxa % 48;

  floatx4 acc[4];
#pragma unroll
  for (int nt = 0; nt < 4; nt++) acc[nt] = (floatx4){0.f, 0.f, 0.f, 0.f};

#pragma unroll
  for (int kk = 0; kk < 2; kk++) {
    int k0 = kk * 32 + quad * 8;
    int ic = k0 >> 4, khp = (k0 >> 3) & 1;
    const unsigned short* src = (ic < 3) ? identp + (b * 3 + ic) * 9800
                                         : hmp + bt * 9800;
    const unsigned short* p = src + (2 * oh + khp * 2) * 100 + 2 * ow;
    UV a;
    a.u.x = *(const unsigned int*)(p);
    a.u.y = *(const unsigned int*)(p + 2);
    a.u.z = *(const unsigned int*)(p + 100);
    a.u.w = *(const unsigned int*)(p + 102);
#pragma unroll
    for (int nt = 0; nt < 4; nt++) {
      UV bv;
      bv.u = *(const uint4*)(w1b + (nt * 16 + l16) * 64 + kk * 32 + quad * 8);
      acc[nt] = __builtin_amdgcn_mfma_f32_16x16x32_bf16(a.s, bv.s, acc[nt], 0, 0, 0);
    }
  }

  float bias[4];
#pragma unroll
  for (int nt = 0; nt < 4; nt++) bias[nt] = b1[nt * 16 + l16];
  unsigned short* sw = stage + wave * 1152;
#pragma unroll
  for (int nt = 0; nt < 4; nt++)
#pragma unroll
    for (int reg = 0; reg < 4; reg++) {
      float v = fmaxf(acc[nt][reg] + bias[nt], 0.f);
      sw[(quad * 4 + reg) * 72 + nt * 16 + l16] = f2bf(v);
    }
  __syncthreads();
  int oh0 = px0 / 48, ow0 = px0 % 48;
  unsigned short* gout = act1cl + (size_t)bt * 166400u + ((oh0 + 1) * 52 + ow0 + 1) * 64;
#pragma unroll
  for (int it = 0; it < 8; it++) {
    int pl = it * 2 + (lane >> 5);
    unsigned int v = *(const unsigned int*)(sw + pl * 72 + (lane & 31) * 2);
    *(unsigned int*)(gout + pl * 64 + (lane & 31) * 2) = v;
  }
}

// ============ conv2 (MFMA, role-swapped): act1cl -> relu -> act2p [26][26][128] ============
__global__ __launch_bounds__(256, 2) void conv2_kernel(
    const unsigned short* __restrict__ act1cl, const unsigned short* __restrict__ w2t,
    const float* __restrict__ b2, unsigned short* __restrict__ act2p) {
  __shared__ unsigned short Blds[2][128 * 40];  // 20480 B
  int tid = threadIdx.x;
  int bx = blockIdx.x, bt = blockIdx.y;
  int wave = tid >> 6, lane = tid & 63, quad = lane >> 4, l16 = lane & 15;
  const unsigned short* frame = act1cl + (size_t)bt * 166400u;
  const unsigned short* abase[3];
#pragma unroll
  for (int mf = 0; mf < 3; mf++) {
    int px = bx * 192 + wave * 48 + mf * 16 + l16;
    int oh = px / 24, ow = px % 24;
    abase[mf] = frame + ((2 * oh) * 52 + 2 * ow) * 64 + quad * 8;
  }
  // contiguous weight staging: thread t reads w2t + kk*4096 + t*16 (lane-linear)
  const unsigned short* bptr = w2t + tid * 16;
  unsigned short* sdst = &Blds[0][0] + (tid >> 1) * 40 + (tid & 1) * 16;

  floatx4 acc[3][8];
#pragma unroll
  for (int mf = 0; mf < 3; mf++)
#pragma unroll
    for (int nt = 0; nt < 8; nt++) acc[mf][nt] = (floatx4){0.f, 0.f, 0.f, 0.f};

  {
    uint4 s0 = *(const uint4*)(bptr);
    uint4 s1 = *(const uint4*)(bptr + 8);
    *(uint4*)(sdst) = s0;
    *(uint4*)(sdst + 8) = s1;
  }
  UV a_cur[3], a_nxt[3];
#pragma unroll
  for (int mf = 0; mf < 3; mf++) a_cur[mf].u = *(const uint4*)(abase[mf]);
  __syncthreads();

#pragma unroll 2
  for (int kk = 0; kk < 32; kk++) {
    int cur = kk & 1;
    UV bf[8];
#pragma unroll
    for (int nt = 0; nt < 8; nt++)
      bf[nt].u = *(const uint4*)(&Blds[cur][(nt * 16 + l16) * 40 + quad * 8]);
    uint4 ns0, ns1;
    if (kk < 31) {
      const unsigned short* p = bptr + (kk + 1) * 4096;
      ns0 = *(const uint4*)(p);
      ns1 = *(const uint4*)(p + 8);
      int tap = (kk + 1) >> 1, ic0 = ((kk + 1) & 1) * 32;
      int kh = tap >> 2, kw = tap & 3;
      int aoff = (kh * 52 + kw) * 64 + ic0;
#pragma unroll
      for (int mf = 0; mf < 3; mf++) a_nxt[mf].u = *(const uint4*)(abase[mf] + aoff);
    }
#pragma unroll
    for (int mf = 0; mf < 3; mf++)
#pragma unroll
      for (int nt = 0; nt < 8; nt++)
        acc[mf][nt] = __builtin_amdgcn_mfma_f32_16x16x32_bf16(a_cur[mf].s, bf[nt].s, acc[mf][nt], 0, 0, 0);
    if (kk < 31) {
      unsigned short* d = sdst + (1 - cur) * 5120;
      *(uint4*)(d) = ns0;
      *(uint4*)(d + 8) = ns1;
    }
    __syncthreads();
#pragma unroll
    for (int mf = 0; mf < 3; mf++) a_cur[mf] = a_nxt[mf];
  }

  float bias[8];
#pragma unroll
  for (int nt = 0; nt < 8; nt++) bias[nt] = b2[nt * 16 + l16];
  unsigned short* sw = &Blds[0][0] + wave * 2176;  // 16 px x 136
  unsigned short* obase = act2p + (size_t)bt * 86528u;
#pragma unroll
  for (int mf = 0; mf < 3; mf++) {
#pragma unroll
    for (int nt = 0; nt < 8; nt++)
#pragma unroll
      for (int reg = 0; reg < 4; reg++) {
        float v = fmaxf(acc[mf][nt][reg] + bias[nt], 0.f);
        sw[(quad * 4 + reg) * 136 + nt * 16 + l16] = f2bf(v);
      }
    __syncthreads();
#pragma unroll
    for (int it = 0; it < 16; it++) {
      unsigned int v = *(const unsigned int*)(sw + it * 136 + lane * 2);
      int px = bx * 192 + wave * 48 + mf * 16 + it;
      int oh = px / 24, ow = px % 24;
      *(unsigned int*)(obase + ((oh + 1) * 26 + ow + 1) * 128 + lane * 2) = v;
    }
    __syncthreads();
  }
}

// ============ deconv3 (MFMA, role-swapped): act2p -> relu -> act3p [50][50][64] ============
__global__ __launch_bounds__(256, 2) void deconv3_kernel(
    const unsigned short* __restrict__ act2p, const unsigned short* __restrict__ w3t,
    const float* __restrict__ b3, unsigned short* __restrict__ act3p) {
  __shared__ unsigned short Blds[2][128 * 40];
  int tid = threadIdx.x;
  int bx = blockIdx.x, r = blockIdx.y, bt = blockIdx.z;
  int wave = tid >> 6, lane = tid & 63, quad = lane >> 4, l16 = lane & 15;
  const unsigned short* a2 = act2p + (size_t)bt * 86528u;
  unsigned short* a3 = act3p + (size_t)bt * 160000u;

  if (bx == 0 && r == 0) {
    uint4* hz = (uint4*)a3;
    uint4 z = {0, 0, 0, 0};
    for (int c = tid; c < 1568; c += 256) {
      int cell = c >> 3, v = c & 7;
      int row, col;
      if (cell < 50) { row = 0; col = cell; }
      else if (cell < 100) { row = 49; col = cell - 50; }
      else if (cell < 148) { row = cell - 99; col = 0; }
      else { row = cell - 147; col = 49; }
      hz[(row * 50 + col) * 8 + v] = z;
    }
  }

  const unsigned short* abase[3];
#pragma unroll
  for (int mf = 0; mf < 3; mf++) {
    int px = bx * 192 + wave * 48 + mf * 16 + l16;
    int i = px / 24, j = px % 24;
    abase[mf] = a2 + ((i + r) * 26 + j) * 128 + quad * 8;
  }
  const unsigned short* bptr = w3t + r * 98304 + tid * 16;
  unsigned short* sdst = &Blds[0][0] + (tid >> 1) * 40 + (tid & 1) * 16;

  floatx4 acc[3][8];
#pragma unroll
  for (int mf = 0; mf < 3; mf++)
#pragma unroll
    for (int nt = 0; nt < 8; nt++) acc[mf][nt] = (floatx4){0.f, 0.f, 0.f, 0.f};

  {
    uint4 s0 = *(const uint4*)(bptr);
    uint4 s1 = *(const uint4*)(bptr + 8);
    *(uint4*)(sdst) = s0;
    *(uint4*)(sdst + 8) = s1;
  }
  UV a_cur[3], a_nxt[3];
#pragma unroll
  for (int mf = 0; mf < 3; mf++) a_cur[mf].u = *(const uint4*)(abase[mf]);
  __syncthreads();

#pragma unroll 2
  for (int kk = 0; kk < 24; kk++) {
    int cur = kk & 1;
    UV bf[8];
#pragma unroll
    for (int nt = 0; nt < 8; nt++)
      bf[nt].u = *(const uint4*)(&Blds[cur][(nt * 16 + l16) * 40 + quad * 8]);
    uint4 ns0, ns1;
    if (kk < 23) {
      const unsigned short* p = bptr + (kk + 1) * 4096;
      ns0 = *(const uint4*)(p);
      ns1 = *(const uint4*)(p + 8);
      int tap = (kk + 1) >> 2, ic0 = ((kk + 1) & 3) * 32;
      int dh = tap / 3, dw = tap - dh * 3;
      int aoff = (dh * 26 + dw) * 128 + ic0;
#pragma unroll
      for (int mf = 0; mf < 3; mf++) a_nxt[mf].u = *(const uint4*)(abase[mf] + aoff);
    }
#pragma unroll
    for (int mf = 0; mf < 3; mf++)
#pragma unroll
      for (int nt = 0; nt < 8; nt++)
        acc[mf][nt] = __builtin_amdgcn_mfma_f32_16x16x32_bf16(a_cur[mf].s, bf[nt].s, acc[mf][nt], 0, 0, 0);
    if (kk < 23) {
      unsigned short* d = sdst + (1 - cur) * 5120;
      *(uint4*)(d) = ns0;
      *(uint4*)(d + 8) = ns1;
    }
    __syncthreads();
#pragma unroll
    for (int mf = 0; mf < 3; mf++) a_cur[mf] = a_nxt[mf];
  }

  float bias[8];
#pragma unroll
  for (int nt = 0; nt < 8; nt++) bias[nt] = b3[(nt * 16 + l16) & 63];
  unsigned short* sw = &Blds[0][0] + wave * 2176;
#pragma unroll
  for (int mf = 0; mf < 3; mf++) {
#pragma unroll
    for (int nt = 0; nt < 8; nt++)
#pragma unroll
      for (int reg = 0; reg < 4; reg++) {
        float v = fmaxf(acc[mf][nt][reg] + bias[nt], 0.f);
        sw[(quad * 4 + reg) * 136 + nt * 16 + l16] = f2bf(v);
      }
    __syncthreads();
#pragma unroll
    for (int it = 0; it < 16; it++) {
      unsigned int v = *(const unsigned int*)(sw + it * 136 + lane * 2);
      int px = bx * 192 + wave * 48 + mf * 16 + it;
      int i = px / 24, j = px % 24;
      *(unsigned int*)(a3 + ((2 * i + r + 1) * 50 + 2 * j + 1) * 64 + lane * 2) = v;
    }
    __syncthreads();
  }
}

// ============ deconv4 v3 (LDS-staged, contiguous loads) + tanh ============
// grid (12, 256): block stages act3p rows i0..i0+5 (chunk-rotated) + w4c into LDS
// with lane-linear uint4 copies; frags via ds_read_b128. Wave w = row i0+w, 3 tiles.
__global__ __launch_bounds__(256) void deconv4_kernel(
    const unsigned short* __restrict__ act3p, const unsigned short* __restrict__ w4c,
    const float* __restrict__ b4, float* __restrict__ out) {
  __shared__ uint4 lds4[2400 + 1168];  // 38400 B act rows + 18688 B w4c (rows padded to 73 uint4)
  int tid = threadIdx.x;
  int wave = tid >> 6, lane = tid & 63, quad = lane >> 4, l16 = lane & 15;
  int bx = blockIdx.x, bt = blockIdx.y;
  int i0 = bx * 4;

  // stage act3p rows i0..i0+5; record rec chunk lc -> physical (lc+rec)&7
  const uint4* src = (const uint4*)(act3p + (size_t)bt * 160000u + i0 * 3200);
#pragma unroll
  for (int v = 0; v < 10; v++) {
    int g = v * 256 + tid;
    if (g < 2400) {
      uint4 d = src[g];
      int row = g / 400;
      int rem = g - row * 400;
      int rec = rem >> 3, lc = rem & 7;
      lds4[row * 400 + rec * 8 + ((lc + rec) & 7)] = d;
    }
  }
  // stage w4c [16][576el] -> rows padded to 73 uint4 (1168 B)
  const uint4* wsrc = (const uint4*)w4c;
#pragma unroll
  for (int v = 0; v < 5; v++) {
    int g = v * 256 + tid;
    if (g < 1152) {
      uint4 d = wsrc[g];
      int n = g / 72, off = g - n * 72;
      lds4[2400 + n * 73 + off] = d;
    }
  }
  __syncthreads();

  const char* alds = (const char*)lds4;
  const char* blds = (const char*)(lds4 + 2400);

  // B-frags once per wave (reused across 3 tiles)
  UV bfr[18];
#pragma unroll
  for (int kk = 0; kk < 18; kk++)
    bfr[kk].u = *(const uint4*)(blds + l16 * 1168 + kk * 64 + quad * 16);

  int i = i0 + wave;  // input row 0..47
  int n = l16;
  int cls = n / 3, oc = n - cls * 3;
  int r = cls >> 1, s = cls & 1;
  float bias = (n < 12) ? b4[oc] : 0.f;
  int oh = 2 * i + r;

#pragma unroll
  for (int t3 = 0; t3 < 3; t3++) {
    int j0 = t3 * 16;
    floatx4 acc = (floatx4){0.f, 0.f, 0.f, 0.f};
#pragma unroll
    for (int kk = 0; kk < 18; kk++) {
      int par = kk & 1, tap = kk >> 1;
      int dh = tap / 3, dw = tap - dh * 3;
      int rec = j0 + dw + l16;
      int pc = (par * 4 + quad + rec) & 7;
      UV a;
      a.u = *(const uint4*)(alds + (wave + dh) * 6400 + rec * 128 + pc * 16);
      acc = __builtin_amdgcn_mfma_f32_16x16x32_bf16(a.s, bfr[kk].s, acc, 0, 0, 0);
    }
    if (n < 12) {
      float* obase = out + (size_t)bt * 27648u + oc * 9216 + oh * 96 + s;
#pragma unroll
      for (int reg = 0; reg < 4; reg++) {
        int jj = j0 + quad * 4 + reg;
        obase[2 * jj] = ftanh(acc[reg] + bias);
      }
    }
  }
}

extern "C" void kernel_launch(void* const* d_in, const int* in_sizes, int n_in,
                              void* d_out, int out_size, void* d_ws, size_t ws_size,
                              hipStream_t stream) {
  const float* ident = (const float*)d_in[0];
  const float* lm = (const float*)d_in[1];
  const float* w1 = (const float*)d_in[2];
  const float* b1 = (const float*)d_in[3];
  const float* w2 = (const float*)d_in[4];
  const float* b2 = (const float*)d_in[5];
  const float* w3 = (const float*)d_in[6];
  const float* b3 = (const float*)d_in[7];
  const float* w4 = (const float*)d_in[8];
  const float* b4 = (const float*)d_in[9];
  float* out = (float*)d_out;
  char* ws = (char*)d_ws;
  unsigned short* identp = (unsigned short*)(ws + IDENTP_OFF);
  unsigned short* hmp = (unsigned short*)(ws + HMP_OFF);
  unsigned short* act1cl = (unsigned short*)(ws + ACT1CL_OFF);
  unsigned short* act2p = (unsigned short*)(ws + ACT2P_OFF);
  unsigned short* act3p = (unsigned short*)(ws + ACT3P_OFF);
  unsigned short* w2t = (unsigned short*)(ws + W2B_OFF);
  unsigned short* w3t = (unsigned short*)(ws + W3B_OFF);
  unsigned short* w1b = (unsigned short*)(ws + W1B_OFF);
  unsigned short* w4c = (unsigned short*)(ws + W4C_OFF);

  prep_kernel<<<dim3(954), 256, 0, stream>>>(lm, ident, w1, w2, w3, w4, identp, hmp,
                                             w1b, w2t, w3t, w4c, act1cl, act2p);
  conv1_kernel<<<dim3(36, 256), 256, 0, stream>>>(identp, hmp, w1b, b1, act1cl);
  conv2_kernel<<<dim3(3, 256), 256, 0, stream>>>(act1cl, w2t, b2, act2p);
  deconv3_kernel<<<dim3(3, 2, 256), 256, 0, stream>>>(act2p, w3t, b3, act3p);
  deconv4_kernel<<<dim3(12, 256), 256, 0, stream>>>(act3p, w4c, b4, out);
}